// Round 1
// baseline (653.618 us; speedup 1.0000x reference)
//
#include <hip/hip_runtime.h>
#include <cmath>

#define NPTS 10000
#define NBATCH 8
#define NFEAT 16
#define DDIM 128
#define NBINS 20
#define BINSZ 500
#define KSEL 5
#define EDGES_PER_BATCH (NPTS*KSEL)        // 50000
#define EDGE_TOT (NBATCH*EDGES_PER_BATCH)  // 400000
#define TOTPTS (NBATCH*NPTS)               // 80000
#define NGRP (NBATCH*NBINS)                // 160
#define PROWS 512                          // padded rows per (grp,ch) partial slab

typedef _Float16 f16x8 __attribute__((ext_vector_type(8)));
typedef float f32x4 __attribute__((ext_vector_type(4)));
typedef unsigned short u16;
typedef unsigned int u32;

// fp32 -> (h, l) with x ~= h + l * 2^-12.  h forced to 0 below fp16 min-normal
// so every stored value is normal/zero (no MFMA denormal-flush exposure).
static __device__ __forceinline__ void split_f16(float v, u16& hu, u16& lu) {
    _Float16 h = (_Float16)v;
    float hf = (float)h;
    if (fabsf(v) < 6.103515625e-05f) { h = (_Float16)0.0f; hf = 0.0f; }
    _Float16 l = (_Float16)((v - hf) * 4096.0f);
    hu = __builtin_bit_cast(u16, h);
    lu = __builtin_bit_cast(u16, l);
}

static __device__ __forceinline__ float f16bits(u16 u) {
    return (float)__builtin_bit_cast(_Float16, u);
}

// enc = ELU(X@W1+b1)@W2+b2, stored as fp16 split pair (He, Le).
// Block 0 also zeroes the bin histogram (k_bins runs after k_enc completes).
__global__ __launch_bounds__(256) void k_enc(const float* __restrict__ X,
        const float* __restrict__ W1, const float* __restrict__ b1,
        const float* __restrict__ W2, const float* __restrict__ b2,
        u16* __restrict__ He, u16* __restrict__ Le, int* __restrict__ hist) {
    __shared__ float hT[128*36];
    const int tid = threadIdx.x;
    const int P0 = blockIdx.x * 32;
    if (blockIdx.x == 0 && tid < NBATCH*NBINS) hist[tid] = 0;
    #pragma unroll
    for (int i = 0; i < 16; ++i) {
        int idx = i*256 + tid;
        int p = idx >> 7;
        int j = idx & 127;
        const float* xr = X + (size_t)(P0 + p)*NFEAT;
        float h = b1[j];
        #pragma unroll
        for (int f = 0; f < 16; ++f) h += xr[f] * W1[f*128 + j];
        h = (h > 0.f) ? h : expm1f(h);
        hT[j*36 + p] = h;
    }
    __syncthreads();
    const int jt = tid & 31, pt = tid >> 5;
    const int j0 = jt*4, p0 = pt*4;
    float acc[4][4];
    #pragma unroll
    for (int ep = 0; ep < 4; ++ep)
        #pragma unroll
        for (int ej = 0; ej < 4; ++ej) acc[ep][ej] = b2[j0+ej];
    for (int k = 0; k < 128; ++k) {
        float4 hv = *(const float4*)&hT[k*36 + p0];
        float4 wv = *(const float4*)&W2[k*128 + j0];
        float hvv[4] = {hv.x,hv.y,hv.z,hv.w};
        float wvv[4] = {wv.x,wv.y,wv.z,wv.w};
        #pragma unroll
        for (int ep = 0; ep < 4; ++ep)
            #pragma unroll
            for (int ej = 0; ej < 4; ++ej) acc[ep][ej] += hvv[ep]*wvv[ej];
    }
    #pragma unroll
    for (int ep = 0; ep < 4; ++ep) {
        u16 hs[4], ls[4];
        #pragma unroll
        for (int ej = 0; ej < 4; ++ej) split_f16(acc[ep][ej], hs[ej], ls[ej]);
        size_t rowoff = (size_t)(P0+p0+ep)*128 + j0;
        uint2 hv2, lv2;
        hv2.x = (u32)hs[0] | ((u32)hs[1]<<16); hv2.y = (u32)hs[2] | ((u32)hs[3]<<16);
        lv2.x = (u32)ls[0] | ((u32)ls[1]<<16); lv2.y = (u32)ls[2] | ((u32)ls[3]<<16);
        *(uint2*)&He[rowoff] = hv2;
        *(uint2*)&Le[rowoff] = lv2;
    }
}

// mul = enc @ R[:, :10]; bin = argmax([mul, -mul]) first-max-wins; histogram.
// enc reconstructed as h + l*2^-12 (error ~2^-22 rel, below bin-argmax gaps).
__global__ __launch_bounds__(256) void k_bins(const u16* __restrict__ He,
        const u16* __restrict__ Le, const float* __restrict__ R,
        int* __restrict__ binIdx, int* __restrict__ hist) {
    __shared__ float Rl[128*10];
    const int tid = threadIdx.x;
    for (int idx = tid; idx < 1280; idx += 256) {
        int d = idx / 10, i = idx % 10;
        Rl[idx] = R[d*100 + i];
    }
    __syncthreads();
    int gp = blockIdx.x*256 + tid;
    if (gp >= TOTPTS) return;
    float acc[10];
    #pragma unroll
    for (int i = 0; i < 10; ++i) acc[i] = 0.f;
    const uint4* hr = (const uint4*)(He + (size_t)gp*128);
    const uint4* lr = (const uint4*)(Le + (size_t)gp*128);
    const float sc = 2.44140625e-4f;
    for (int c = 0; c < 16; ++c) {
        uint4 hv = hr[c], lv = lr[c];
        float x[8];
        x[0] = f16bits((u16)(hv.x & 0xffff)) + f16bits((u16)(lv.x & 0xffff))*sc;
        x[1] = f16bits((u16)(hv.x >> 16))    + f16bits((u16)(lv.x >> 16))*sc;
        x[2] = f16bits((u16)(hv.y & 0xffff)) + f16bits((u16)(lv.y & 0xffff))*sc;
        x[3] = f16bits((u16)(hv.y >> 16))    + f16bits((u16)(lv.y >> 16))*sc;
        x[4] = f16bits((u16)(hv.z & 0xffff)) + f16bits((u16)(lv.z & 0xffff))*sc;
        x[5] = f16bits((u16)(hv.z >> 16))    + f16bits((u16)(lv.z >> 16))*sc;
        x[6] = f16bits((u16)(hv.w & 0xffff)) + f16bits((u16)(lv.w & 0xffff))*sc;
        x[7] = f16bits((u16)(hv.w >> 16))    + f16bits((u16)(lv.w >> 16))*sc;
        #pragma unroll
        for (int e = 0; e < 8; ++e) {
            const float* rr = &Rl[(c*8+e)*10];
            #pragma unroll
            for (int i = 0; i < 10; ++i) acc[i] += x[e]*rr[i];
        }
    }
    float best = acc[0]; int bi = 0;
    #pragma unroll
    for (int i = 1; i < 10; ++i) if (acc[i] > best) { best = acc[i]; bi = i; }
    #pragma unroll
    for (int i = 0; i < 10; ++i) { float v = -acc[i]; if (v > best) { best = v; bi = 10+i; } }
    binIdx[gp] = bi;
    atomicAdd(&hist[(gp/NPTS)*NBINS + bi], 1);
}

// stable counting-sort scatter: one block per (batch,bin)
__global__ __launch_bounds__(256) void k_sort(const int* __restrict__ binIdx,
        const int* __restrict__ hist, int* __restrict__ sortedIdx) {
    const int b = blockIdx.x / NBINS;
    const int bin = blockIdx.x % NBINS;
    const int tid = threadIdx.x;
    __shared__ int wtot[4];
    int off = 0;
    for (int k = 0; k < bin; ++k) off += hist[b*NBINS + k];
    const int* bptr = binIdx + b*NPTS;
    int* sptr = sortedIdx + b*NPTS;
    const int lane = tid & 63, wid = tid >> 6;
    for (int c = 0; c < 40; ++c) {
        int i = c*256 + tid;
        bool pred = (i < NPTS) && (bptr[i] == bin);
        unsigned long long mask = __ballot(pred);
        int rank = __popcll(mask & ((1ULL << lane) - 1ULL));
        if (lane == 0) wtot[wid] = __popcll(mask);
        __syncthreads();
        int prefix = 0;
        #pragma unroll
        for (int w = 0; w < 4; ++w) prefix += (w < wid) ? wtot[w] : 0;
        int total = wtot[0]+wtot[1]+wtot[2]+wtot[3];
        if (pred) sptr[off + prefix + rank] = i;
        off += total;
        __syncthreads();
    }
}

// insert (v,p) into sorted-desc 5-list, strict > (candidates arrive ascending p)
#define INS_STRICT(VV,PP,v,p) do { \
  if ((v) > VV[4]) { \
    if ((v) > VV[3]) { VV[4]=VV[3]; PP[4]=PP[3]; \
      if ((v) > VV[2]) { VV[3]=VV[2]; PP[3]=PP[2]; \
        if ((v) > VV[1]) { VV[2]=VV[1]; PP[2]=PP[1]; \
          if ((v) > VV[0]) { VV[1]=VV[0]; PP[1]=PP[0]; VV[0]=(v); PP[0]=(p); } \
          else { VV[1]=(v); PP[1]=(p); } } \
        else { VV[2]=(v); PP[2]=(p); } } \
      else { VV[3]=(v); PP[3]=(p); } } \
    else { VV[4]=(v); PP[4]=(p); } } } while(0)

// tie-aware better-than: (v desc, p asc) — exact lax.top_k semantics
#define BT(va,pa,vb,pb) (((va) > (vb)) || (((va) == (vb)) && ((pa) < (pb))))
#define INS_TIE(VV,PP,v,p) do { \
  if (BT(v,p,VV[4],PP[4])) { \
    if (BT(v,p,VV[3],PP[3])) { VV[4]=VV[3]; PP[4]=PP[3]; \
      if (BT(v,p,VV[2],PP[2])) { VV[3]=VV[2]; PP[3]=PP[2]; \
        if (BT(v,p,VV[1],PP[1])) { VV[2]=VV[1]; PP[2]=PP[1]; \
          if (BT(v,p,VV[0],PP[0])) { VV[1]=VV[0]; PP[1]=PP[0]; VV[0]=(v); PP[0]=(p); } \
          else { VV[1]=(v); PP[1]=(p); } } \
        else { VV[2]=(v); PP[2]=(p); } } \
      else { VV[3]=(v); PP[3]=(p); } } \
    else { VV[4]=(v); PP[4]=(p); } } } while(0)

// Gram via f16 MFMA, two-component split: S = H·H^T + 2^-12 (H·L^T + L·H^T).
// Same grid/decomposition as the fp32 version (blockIdx = unit*160 + grp,
// r3-verified XCD mapping; 16 units of 128x128 per group) and same pV/pP
// partial interface, so k_sort / k_edge are unchanged.
// 4 waves/block; each wave owns 32 rows x 128 cols = 2x8 frags of 16x16, K=128
// in 4 steps of 32. Fragment layout (mfma_f32_16x16x32_f16, m92 "B^T" pattern):
// A/B lane l holds point (base + (l&15)), k = ks*32 + (l>>4)*8 + e (8 contig).
// C/D: col = lane&15, row = (lane>>4)*4 + reg (m89/m91-verified, dtype-indep).
// Operands load straight from global: per-kstep B set is 16 KB -> L1-resident.
__global__ __launch_bounds__(256, 2) void k_gram(const u16* __restrict__ He,
        const u16* __restrict__ Le, const int* __restrict__ sortedIdx,
        float* __restrict__ pV, int* __restrict__ pP) {
    __shared__ int gIdx[512];
    const int tid = threadIdx.x;
    const int unit = blockIdx.x / 160;      // rowTile*4 + ch
    const int grp  = blockIdx.x - unit*160;
    const int rowTile = unit >> 2, ch = unit & 3;
    const int b = grp / NBINS, g = grp - b*NBINS;
    for (int i = tid; i < 512; i += 256) gIdx[i] = sortedIdx[b*NPTS + g*500 + min(i, 499)];
    __syncthreads();

    const int w    = tid >> 6;              // wave 0..3: rows w*32..w*32+31
    const int lane = tid & 63;
    const int l15  = lane & 15, l4 = lane >> 4;
    const int rowBase = rowTile * 128;

    const int pa0 = gIdx[rowBase + w*32 +      l15];
    const int pa1 = gIdx[rowBase + w*32 + 16 + l15];
    int pb[8];
    #pragma unroll
    for (int cf = 0; cf < 8; ++cf) pb[cf] = gIdx[ch*128 + cf*16 + l15];

    const size_t ebase = (size_t)b * NPTS * 128;
    const u16* HB = He + ebase;             // wave-uniform -> SGPR base
    const u16* LB = Le + ebase;
    const int obA0 = pa0 * 128;
    const int obA1 = pa1 * 128;

    f32x4 accH[2][8], accX[2][8];
    const f32x4 z4 = {0.f, 0.f, 0.f, 0.f};
    #pragma unroll
    for (int rf = 0; rf < 2; ++rf)
        #pragma unroll
        for (int cf = 0; cf < 8; ++cf) { accH[rf][cf] = z4; accX[rf][cf] = z4; }

    #pragma unroll 1
    for (int ks = 0; ks < 4; ++ks) {
        const int k0 = ks*32 + l4*8;
        const f16x8 aH0 = *(const f16x8*)(HB + obA0 + k0);
        const f16x8 aL0 = *(const f16x8*)(LB + obA0 + k0);
        const f16x8 aH1 = *(const f16x8*)(HB + obA1 + k0);
        const f16x8 aL1 = *(const f16x8*)(LB + obA1 + k0);
        #pragma unroll
        for (int cf = 0; cf < 8; ++cf) {
            const int ob = pb[cf]*128 + k0;
            const f16x8 bh = *(const f16x8*)(HB + ob);
            const f16x8 bl = *(const f16x8*)(LB + ob);
            accH[0][cf] = __builtin_amdgcn_mfma_f32_16x16x32_f16(aH0, bh, accH[0][cf], 0, 0, 0);
            accH[1][cf] = __builtin_amdgcn_mfma_f32_16x16x32_f16(aH1, bh, accH[1][cf], 0, 0, 0);
            accX[0][cf] = __builtin_amdgcn_mfma_f32_16x16x32_f16(aL0, bh, accX[0][cf], 0, 0, 0);
            accX[1][cf] = __builtin_amdgcn_mfma_f32_16x16x32_f16(aL1, bh, accX[1][cf], 0, 0, 0);
            accX[0][cf] = __builtin_amdgcn_mfma_f32_16x16x32_f16(aH0, bl, accX[0][cf], 0, 0, 0);
            accX[1][cf] = __builtin_amdgcn_mfma_f32_16x16x32_f16(aH1, bl, accX[1][cf], 0, 0, 0);
        }
    }

    // top-5 per row: per-lane insert of its 8 cf-values (ascending cpos ->
    // strict), then 4-step xor-butterfly tie-aware merge over the 16 lanes
    // (same l4 group) that share each row.
    const float sc = 2.44140625e-4f;
    #pragma unroll
    for (int rf = 0; rf < 2; ++rf) {
        #pragma unroll
        for (int j = 0; j < 4; ++j) {
            const int rpos = rowBase + w*32 + rf*16 + l4*4 + j;
            float lv[5]; int lp[5];
            #pragma unroll
            for (int q = 0; q < 5; ++q) { lv[q] = -3.4e38f; lp[q] = 0x7fffffff; }
            #pragma unroll
            for (int cf = 0; cf < 8; ++cf) {
                const int cpos = ch*128 + cf*16 + l15;
                const float v = accH[rf][cf][j] + accX[rf][cf][j] * sc;
                if (cpos < 500) INS_STRICT(lv, lp, v, cpos);
            }
            #pragma unroll
            for (int m = 1; m < 16; m <<= 1) {
                float qv[5]; int qp[5];
                #pragma unroll
                for (int q = 0; q < 5; ++q) {
                    qv[q] = __shfl_xor(lv[q], m, 64);
                    qp[q] = __shfl_xor(lp[q], m, 64);
                }
                #pragma unroll
                for (int q = 0; q < 5; ++q) INS_TIE(lv, lp, qv[q], qp[q]);
            }
            if (l15 == 0 && rpos < 500) {
                const int base = ((grp*4 + ch)*PROWS + rpos)*5;
                #pragma unroll
                for (int q = 0; q < 5; ++q) { pV[base+q] = lv[q]; pP[base+q] = lp[q]; }
            }
        }
    }
}

// fused merge + edge MLP, 4 threads per src point (j-loop split in 32-chunks,
// pairwise shfl_xor sum — summation-order change only, within edge tolerance).
__global__ __launch_bounds__(256) void k_edge(const float* __restrict__ X,
        const float* __restrict__ W1, const float* __restrict__ b1,
        const float* __restrict__ W2, const float* __restrict__ b2,
        const float* __restrict__ pV, const int* __restrict__ pP,
        const int* __restrict__ sortedIdx, float* __restrict__ out) {
    __shared__ float w1t[128*36];
    __shared__ float b1l[128];
    __shared__ float w2l[128];
    const int tid = threadIdx.x;
    for (int idx = tid; idx < 33*128; idx += 256) {
        int f = idx >> 7, j = idx & 127;
        w1t[j*36 + f] = W1[idx];
    }
    if (tid < 128) { b1l[tid] = b1[tid]; w2l[tid] = W2[tid]; }
    __syncthreads();
    int rid4 = blockIdx.x*256 + tid;
    if (rid4 >= NGRP*BINSZ*4) return;
    const int rid = rid4 >> 2, quarter = rid4 & 3;
    const int grp = rid / BINSZ;
    const int rowLocal = rid - grp*BINSZ;
    const int b = grp / NBINS, g = grp - b*NBINS;
    // ---- merge 4 ch-partials (duplicated across the 4 quarters; deterministic) ----
    float lv[5]; int lp[5];
    {
        int pbase = (grp*4*PROWS + rowLocal)*5;
        #pragma unroll
        for (int j = 0; j < 5; ++j) { lv[j] = pV[pbase+j]; lp[j] = pP[pbase+j]; }
    }
    #pragma unroll
    for (int chh = 1; chh < 4; ++chh) {
        int pbase = ((grp*4 + chh)*PROWS + rowLocal)*5;
        #pragma unroll
        for (int j = 0; j < 5; ++j) {
            float v = pV[pbase+j]; int p = pP[pbase+j];
            INS_TIE(lv, lp, v, p);
        }
    }
    const int* sIdx = sortedIdx + b*NPTS + g*BINSZ;
    const int src = sIdx[rowLocal];
    int dd[5]; float vv[5];
    #pragma unroll
    for (int j = 0; j < 5; ++j) {
        dd[j] = sIdx[lp[j]];
        vv[j] = 1.f/(1.f + expf(-lv[j]));
    }
    #define CSWAP(i,j) { if (dd[i] > dd[j]) { int td=dd[i];dd[i]=dd[j];dd[j]=td; \
                         float tf=vv[i];vv[i]=vv[j];vv[j]=tf; } }
    CSWAP(0,1) CSWAP(3,4) CSWAP(2,4) CSWAP(2,3) CSWAP(1,4)
    CSWAP(0,3) CSWAP(0,2) CSWAP(1,3) CSWAP(1,2)
    #undef CSWAP
    const int base = b*EDGES_PER_BATCH + src*5;
    if (quarter == 0) {
        #pragma unroll
        for (int e = 0; e < 5; ++e) {
            out[EDGE_TOT   + base + e] = (float)src;
            out[2*EDGE_TOT + base + e] = (float)dd[e];
        }
    }
    // ---- edge MLP over j-range [quarter*32, quarter*32+32) ----
    float4 xs[4];
    {
        const float4* xp = (const float4*)(X + ((size_t)b*NPTS + src)*NFEAT);
        #pragma unroll
        for (int q = 0; q < 4; ++q) xs[q] = xp[q];
    }
    float4 xd[5][4];
    #pragma unroll
    for (int e = 0; e < 5; ++e) {
        const float4* xp = (const float4*)(X + ((size_t)b*NPTS + dd[e])*NFEAT);
        #pragma unroll
        for (int q = 0; q < 4; ++q) xd[e][q] = xp[q];
    }
    float acc[5] = {0.f,0.f,0.f,0.f,0.f};
    const int jEnd = quarter*32 + 32;
    for (int j = quarter*32; j < jEnd; ++j) {
        const float* wr = &w1t[j*36];
        float4 ws0 = ((const float4*)wr)[0];
        float4 ws1 = ((const float4*)wr)[1];
        float4 ws2 = ((const float4*)wr)[2];
        float4 ws3 = ((const float4*)wr)[3];
        float4 u0  = ((const float4*)(wr+16))[0];
        float4 u1  = ((const float4*)(wr+16))[1];
        float4 u2  = ((const float4*)(wr+16))[2];
        float4 u3  = ((const float4*)(wr+16))[3];
        float w32 = wr[32];
        float w2j = w2l[j];
        float sh = b1l[j]
            + xs[0].x*ws0.x + xs[0].y*ws0.y + xs[0].z*ws0.z + xs[0].w*ws0.w
            + xs[1].x*ws1.x + xs[1].y*ws1.y + xs[1].z*ws1.z + xs[1].w*ws1.w
            + xs[2].x*ws2.x + xs[2].y*ws2.y + xs[2].z*ws2.z + xs[2].w*ws2.w
            + xs[3].x*ws3.x + xs[3].y*ws3.y + xs[3].z*ws3.z + xs[3].w*ws3.w;
        #pragma unroll
        for (int e = 0; e < 5; ++e) {
            float h = sh
                + xd[e][0].x*u0.x + xd[e][0].y*u0.y + xd[e][0].z*u0.z + xd[e][0].w*u0.w
                + xd[e][1].x*u1.x + xd[e][1].y*u1.y + xd[e][1].z*u1.z + xd[e][1].w*u1.w
                + xd[e][2].x*u2.x + xd[e][2].y*u2.y + xd[e][2].z*u2.z + xd[e][2].w*u2.w
                + xd[e][3].x*u3.x + xd[e][3].y*u3.y + xd[e][3].z*u3.z + xd[e][3].w*u3.w;
            h += vv[e]*w32;
            h = (h > 0.f) ? h : expm1f(h);
            acc[e] += h * w2j;
        }
    }
    // pairwise reduce across the 4 quarters: ((q0+q1)+(q2+q3))
    #pragma unroll
    for (int e = 0; e < 5; ++e) {
        acc[e] += __shfl_xor(acc[e], 1, 64);
        acc[e] += __shfl_xor(acc[e], 2, 64);
    }
    if (quarter != 0) return;
    float b2v = b2[0];
    #pragma unroll
    for (int e = 0; e < 5; ++e) {
        out[base + e] = 1.f/(1.f + expf(-(acc[e] + b2v)));
    }
}

extern "C" void kernel_launch(void* const* d_in, const int* in_sizes, int n_in,
                              void* d_out, int out_size, void* d_ws, size_t ws_size,
                              hipStream_t stream) {
    const float* X   = (const float*)d_in[0];
    const float* We1 = (const float*)d_in[1];
    const float* be1 = (const float*)d_in[2];
    const float* We2 = (const float*)d_in[3];
    const float* be2 = (const float*)d_in[4];
    const float* Wd1 = (const float*)d_in[5];
    const float* bd1 = (const float*)d_in[6];
    const float* Wd2 = (const float*)d_in[7];
    const float* bd2 = (const float*)d_in[8];
    const float* R   = (const float*)d_in[9];
    float* out = (float*)d_out;

    // workspace layout (~54 MB, unchanged footprint):
    // He+Le (2 x ushort TOTPTS*128) occupy exactly the old f32 enc slab.
    u16* He         = (u16*)d_ws;                          // 80000*128 u16
    u16* Le         = He + (size_t)TOTPTS*128;             // 80000*128 u16
    int*   binIdx   = (int*)(Le + (size_t)TOTPTS*128);     // 80000
    int*   sortedIdx= binIdx + TOTPTS;                     // 80000
    int*   hist     = sortedIdx + TOTPTS;                  // 160
    float* pV       = (float*)(hist + NBATCH*NBINS);       // 160*4*512*5
    int*   pP       = (int*)(pV + (size_t)NGRP*4*PROWS*5); // 160*4*512*5

    k_enc  <<<TOTPTS/32, 256, 0, stream>>>(X, We1, be1, We2, be2, He, Le, hist);
    k_bins <<<(TOTPTS+255)/256, 256, 0, stream>>>(He, Le, R, binIdx, hist);
    k_sort <<<NBATCH*NBINS, 256, 0, stream>>>(binIdx, hist, sortedIdx);
    k_gram <<<NGRP*16, 256, 0, stream>>>(He, Le, sortedIdx, pV, pP);
    k_edge <<<(NGRP*BINSZ*4+255)/256, 256, 0, stream>>>(X, Wd1, bd1, Wd2, bd2,
                                                        pV, pP, sortedIdx, out);
}

// Round 2
// 495.830 us; speedup vs baseline: 1.3182x; 1.3182x over previous
//
#include <hip/hip_runtime.h>
#include <cmath>

#define NPTS 10000
#define NBATCH 8
#define NFEAT 16
#define DDIM 128
#define NBINS 20
#define BINSZ 500
#define KSEL 5
#define EDGES_PER_BATCH (NPTS*KSEL)        // 50000
#define EDGE_TOT (NBATCH*EDGES_PER_BATCH)  // 400000
#define TOTPTS (NBATCH*NPTS)               // 80000
#define NGRP (NBATCH*NBINS)                // 160
#define PROWS 512                          // padded rows per (grp,ch) partial slab

typedef _Float16 f16x8 __attribute__((ext_vector_type(8)));
typedef float f32x4 __attribute__((ext_vector_type(4)));
typedef unsigned short u16;
typedef unsigned int u32;

// fp32 -> (h, l) with x ~= h + l * 2^-12.  h forced to 0 below fp16 min-normal
// so every stored value is normal/zero (no MFMA denormal-flush exposure).
static __device__ __forceinline__ void split_f16(float v, u16& hu, u16& lu) {
    _Float16 h = (_Float16)v;
    float hf = (float)h;
    if (fabsf(v) < 6.103515625e-05f) { h = (_Float16)0.0f; hf = 0.0f; }
    _Float16 l = (_Float16)((v - hf) * 4096.0f);
    hu = __builtin_bit_cast(u16, h);
    lu = __builtin_bit_cast(u16, l);
}

static __device__ __forceinline__ float f16bits(u16 u) {
    return (float)__builtin_bit_cast(_Float16, u);
}

// enc = ELU(X@W1+b1)@W2+b2, stored as P[row][256] = [H(128) | L(128)] f16.
// Block 0 also zeroes the bin histogram (k_bins runs after k_enc completes).
__global__ __launch_bounds__(256) void k_enc(const float* __restrict__ X,
        const float* __restrict__ W1, const float* __restrict__ b1,
        const float* __restrict__ W2, const float* __restrict__ b2,
        u16* __restrict__ P, int* __restrict__ hist) {
    __shared__ float hT[128*36];
    const int tid = threadIdx.x;
    const int P0 = blockIdx.x * 32;
    if (blockIdx.x == 0 && tid < NBATCH*NBINS) hist[tid] = 0;
    #pragma unroll
    for (int i = 0; i < 16; ++i) {
        int idx = i*256 + tid;
        int p = idx >> 7;
        int j = idx & 127;
        const float* xr = X + (size_t)(P0 + p)*NFEAT;
        float h = b1[j];
        #pragma unroll
        for (int f = 0; f < 16; ++f) h += xr[f] * W1[f*128 + j];
        h = (h > 0.f) ? h : expm1f(h);
        hT[j*36 + p] = h;
    }
    __syncthreads();
    const int jt = tid & 31, pt = tid >> 5;
    const int j0 = jt*4, p0 = pt*4;
    float acc[4][4];
    #pragma unroll
    for (int ep = 0; ep < 4; ++ep)
        #pragma unroll
        for (int ej = 0; ej < 4; ++ej) acc[ep][ej] = b2[j0+ej];
    for (int k = 0; k < 128; ++k) {
        float4 hv = *(const float4*)&hT[k*36 + p0];
        float4 wv = *(const float4*)&W2[k*128 + j0];
        float hvv[4] = {hv.x,hv.y,hv.z,hv.w};
        float wvv[4] = {wv.x,wv.y,wv.z,wv.w};
        #pragma unroll
        for (int ep = 0; ep < 4; ++ep)
            #pragma unroll
            for (int ej = 0; ej < 4; ++ej) acc[ep][ej] += hvv[ep]*wvv[ej];
    }
    #pragma unroll
    for (int ep = 0; ep < 4; ++ep) {
        u16 hs[4], ls[4];
        #pragma unroll
        for (int ej = 0; ej < 4; ++ej) split_f16(acc[ep][ej], hs[ej], ls[ej]);
        size_t ro = (size_t)(P0+p0+ep)*256 + j0;
        uint2 hv2, lv2;
        hv2.x = (u32)hs[0] | ((u32)hs[1]<<16); hv2.y = (u32)hs[2] | ((u32)hs[3]<<16);
        lv2.x = (u32)ls[0] | ((u32)ls[1]<<16); lv2.y = (u32)ls[2] | ((u32)ls[3]<<16);
        *(uint2*)&P[ro]       = hv2;
        *(uint2*)&P[ro + 128] = lv2;
    }
}

// mul = enc @ R[:, :10]; bin = argmax([mul, -mul]) first-max-wins; histogram.
// enc reconstructed as h + l*2^-12 (error ~2^-22 rel, below bin-argmax gaps).
__global__ __launch_bounds__(256) void k_bins(const u16* __restrict__ P,
        const float* __restrict__ R,
        int* __restrict__ binIdx, int* __restrict__ hist) {
    __shared__ float Rl[128*10];
    const int tid = threadIdx.x;
    for (int idx = tid; idx < 1280; idx += 256) {
        int d = idx / 10, i = idx % 10;
        Rl[idx] = R[d*100 + i];
    }
    __syncthreads();
    int gp = blockIdx.x*256 + tid;
    if (gp >= TOTPTS) return;
    float acc[10];
    #pragma unroll
    for (int i = 0; i < 10; ++i) acc[i] = 0.f;
    const uint4* hr = (const uint4*)(P + (size_t)gp*256);
    const uint4* lr = (const uint4*)(P + (size_t)gp*256 + 128);
    const float sc = 2.44140625e-4f;
    for (int c = 0; c < 16; ++c) {
        uint4 hv = hr[c], lv = lr[c];
        float x[8];
        x[0] = f16bits((u16)(hv.x & 0xffff)) + f16bits((u16)(lv.x & 0xffff))*sc;
        x[1] = f16bits((u16)(hv.x >> 16))    + f16bits((u16)(lv.x >> 16))*sc;
        x[2] = f16bits((u16)(hv.y & 0xffff)) + f16bits((u16)(lv.y & 0xffff))*sc;
        x[3] = f16bits((u16)(hv.y >> 16))    + f16bits((u16)(lv.y >> 16))*sc;
        x[4] = f16bits((u16)(hv.z & 0xffff)) + f16bits((u16)(lv.z & 0xffff))*sc;
        x[5] = f16bits((u16)(hv.z >> 16))    + f16bits((u16)(lv.z >> 16))*sc;
        x[6] = f16bits((u16)(hv.w & 0xffff)) + f16bits((u16)(lv.w & 0xffff))*sc;
        x[7] = f16bits((u16)(hv.w >> 16))    + f16bits((u16)(lv.w >> 16))*sc;
        #pragma unroll
        for (int e = 0; e < 8; ++e) {
            const float* rr = &Rl[(c*8+e)*10];
            #pragma unroll
            for (int i = 0; i < 10; ++i) acc[i] += x[e]*rr[i];
        }
    }
    float best = acc[0]; int bi = 0;
    #pragma unroll
    for (int i = 1; i < 10; ++i) if (acc[i] > best) { best = acc[i]; bi = i; }
    #pragma unroll
    for (int i = 0; i < 10; ++i) { float v = -acc[i]; if (v > best) { best = v; bi = 10+i; } }
    binIdx[gp] = bi;
    atomicAdd(&hist[(gp/NPTS)*NBINS + bi], 1);
}

// stable counting-sort scatter: one block per (batch,bin)
__global__ __launch_bounds__(256) void k_sort(const int* __restrict__ binIdx,
        const int* __restrict__ hist, int* __restrict__ sortedIdx) {
    const int b = blockIdx.x / NBINS;
    const int bin = blockIdx.x % NBINS;
    const int tid = threadIdx.x;
    __shared__ int wtot[4];
    int off = 0;
    for (int k = 0; k < bin; ++k) off += hist[b*NBINS + k];
    const int* bptr = binIdx + b*NPTS;
    int* sptr = sortedIdx + b*NPTS;
    const int lane = tid & 63, wid = tid >> 6;
    for (int c = 0; c < 40; ++c) {
        int i = c*256 + tid;
        bool pred = (i < NPTS) && (bptr[i] == bin);
        unsigned long long mask = __ballot(pred);
        int rank = __popcll(mask & ((1ULL << lane) - 1ULL));
        if (lane == 0) wtot[wid] = __popcll(mask);
        __syncthreads();
        int prefix = 0;
        #pragma unroll
        for (int w = 0; w < 4; ++w) prefix += (w < wid) ? wtot[w] : 0;
        int total = wtot[0]+wtot[1]+wtot[2]+wtot[3];
        if (pred) sptr[off + prefix + rank] = i;
        off += total;
        __syncthreads();
    }
}

// tie-aware better-than: (v desc, p asc) — exact lax.top_k semantics
#define BT(va,pa,vb,pb) (((va) > (vb)) || (((va) == (vb)) && ((pa) < (pb))))
#define INS_TIE(VV,PP,v,p) do { \
  if (BT(v,p,VV[4],PP[4])) { \
    if (BT(v,p,VV[3],PP[3])) { VV[4]=VV[3]; PP[4]=PP[3]; \
      if (BT(v,p,VV[2],PP[2])) { VV[3]=VV[2]; PP[3]=PP[2]; \
        if (BT(v,p,VV[1],PP[1])) { VV[2]=VV[1]; PP[2]=PP[1]; \
          if (BT(v,p,VV[0],PP[0])) { VV[1]=VV[0]; PP[1]=PP[0]; VV[0]=(v); PP[0]=(p); } \
          else { VV[1]=(v); PP[1]=(p); } } \
        else { VV[2]=(v); PP[2]=(p); } } \
      else { VV[3]=(v); PP[3]=(p); } } \
    else { VV[4]=(v); PP[4]=(p); } } } while(0)

// Gram via f16 MFMA, single accumulator per tile:
//   acc = H_a·L_b^T + L_a·H_b^T + (64H_a)·(64H_b)^T ;  S = acc·2^-12
//       = hh + 2^-12(h·l_b + l_a·h)        [identical to the verified 3-pass formula]
// Fragment roles HW-verified in round 1 (passed, absmax == fp32 version):
//   A/B lane l holds point (base + (l&15)), k = ks*32 + (l>>4)*8 + e (8 contig)
//   C/D: col = lane&15, row = (lane>>4)*4 + reg.
// Epilogue: scatter S-tile (x2^-12) to LDS T[64][132] per rf-half (2-way-free
// writes), then 4 threads/row top-5 over 32 contiguous cols + 2-step shfl merge
// — replaces the 16-lane butterfly that made round 1 VALU-bound.
__global__ __launch_bounds__(256, 3) void k_gram(const u16* __restrict__ P,
        const int* __restrict__ sortedIdx, float* __restrict__ pV, int* __restrict__ pP) {
    __shared__ int gIdx[512];
    __shared__ float T[64][132];
    const int tid = threadIdx.x;
    const int unit = blockIdx.x / 160;      // rowTile*4 + ch
    const int grp  = blockIdx.x - unit*160;
    const int rowTile = unit >> 2, ch = unit & 3;
    const int b = grp / NBINS, g = grp - b*NBINS;
    for (int i = tid; i < 512; i += 256) gIdx[i] = sortedIdx[b*NPTS + g*500 + min(i, 499)];
    __syncthreads();

    const int w    = tid >> 6;              // wave 0..3: rows w*32..w*32+31
    const int lane = tid & 63;
    const int l15  = lane & 15, l4 = lane >> 4;
    const int rowBase = rowTile * 128;

    const size_t ebase = (size_t)b * NPTS * 256;   // halfwords
    const u16* PB = P + ebase;
    const u16* pA0 = PB + (size_t)gIdx[rowBase + w*32 +      l15]*256 + l4*8;
    const u16* pA1 = PB + (size_t)gIdx[rowBase + w*32 + 16 + l15]*256 + l4*8;
    const u16* pBc[8];
    #pragma unroll
    for (int cf = 0; cf < 8; ++cf) pBc[cf] = PB + (size_t)gIdx[ch*128 + cf*16 + l15]*256 + l4*8;

    f32x4 acc[2][8];
    const f32x4 z4 = {0.f, 0.f, 0.f, 0.f};
    #pragma unroll
    for (int rf = 0; rf < 2; ++rf)
        #pragma unroll
        for (int cf = 0; cf < 8; ++cf) acc[rf][cf] = z4;

    const _Float16 c64 = (_Float16)64.0f;
    #pragma unroll 1
    for (int ks = 0; ks < 4; ++ks) {
        const int oH = ks*32, oL = 128 + ks*32;
        const f16x8 aH0 = *(const f16x8*)(pA0 + oH);
        const f16x8 aL0 = *(const f16x8*)(pA0 + oL);
        const f16x8 aH1 = *(const f16x8*)(pA1 + oH);
        const f16x8 aL1 = *(const f16x8*)(pA1 + oL);
        const f16x8 aS0 = aH0 * c64;
        const f16x8 aS1 = aH1 * c64;
        #pragma unroll
        for (int cf = 0; cf < 8; ++cf) {
            const f16x8 bH = *(const f16x8*)(pBc[cf] + oH);
            const f16x8 bL = *(const f16x8*)(pBc[cf] + oL);
            const f16x8 bS = bH * c64;
            acc[0][cf] = __builtin_amdgcn_mfma_f32_16x16x32_f16(aH0, bL, acc[0][cf], 0, 0, 0);
            acc[1][cf] = __builtin_amdgcn_mfma_f32_16x16x32_f16(aH1, bL, acc[1][cf], 0, 0, 0);
            acc[0][cf] = __builtin_amdgcn_mfma_f32_16x16x32_f16(aL0, bH, acc[0][cf], 0, 0, 0);
            acc[1][cf] = __builtin_amdgcn_mfma_f32_16x16x32_f16(aL1, bH, acc[1][cf], 0, 0, 0);
            acc[0][cf] = __builtin_amdgcn_mfma_f32_16x16x32_f16(aS0, bS, acc[0][cf], 0, 0, 0);
            acc[1][cf] = __builtin_amdgcn_mfma_f32_16x16x32_f16(aS1, bS, acc[1][cf], 0, 0, 0);
        }
    }

    // ---- epilogue: per rf-half, LDS transpose then 4-thread/row top-5 ----
    const float sc = 2.44140625e-4f;        // 2^-12
    const int rT = tid >> 2;                // 0..63: T-row this thread reduces
    const int q  = tid & 3;                 // quarter: cols q*32..q*32+31
    const int nI = (ch == 3 && q == 3) ? 20 : 32;   // cols valid (<500) this quarter
    #pragma unroll
    for (int rf = 0; rf < 2; ++rf) {
        #pragma unroll
        for (int cf = 0; cf < 8; ++cf) {
            const int col = cf*16 + l15;
            const int r0  = w*16 + l4*4;
            #pragma unroll
            for (int j = 0; j < 4; ++j) T[r0+j][col] = acc[rf][cf][j] * sc;
        }
        __syncthreads();
        float lv[5]; int lp[5];
        #pragma unroll
        for (int p5 = 0; p5 < 5; ++p5) { lv[p5] = -3.4e38f; lp[p5] = 0x7fffffff; }
        const float* Tr = &T[rT][q*32];
        #pragma unroll
        for (int t = 0; t < 8; ++t) {
            const int c4 = (t + q*2) & 7;   // bank-rotated visit order
            float4 v4 = *(const float4*)&Tr[c4*4];
            float vv4[4] = {v4.x, v4.y, v4.z, v4.w};
            #pragma unroll
            for (int e = 0; e < 4; ++e) {
                const int i = c4*4 + e;
                if (i < nI) INS_TIE(lv, lp, vv4[e], ch*128 + q*32 + i);
            }
        }
        #pragma unroll
        for (int m = 1; m < 4; m <<= 1) {
            float qv[5]; int qp[5];
            #pragma unroll
            for (int p5 = 0; p5 < 5; ++p5) {
                qv[p5] = __shfl_xor(lv[p5], m, 64);
                qp[p5] = __shfl_xor(lp[p5], m, 64);
            }
            #pragma unroll
            for (int p5 = 0; p5 < 5; ++p5) INS_TIE(lv, lp, qv[p5], qp[p5]);
        }
        if (q == 0) {
            const int rpos = rowBase + (rT>>4)*32 + rf*16 + (rT&15);
            if (rpos < 500) {
                const int pbase = ((grp*4 + ch)*PROWS + rpos)*5;
                #pragma unroll
                for (int p5 = 0; p5 < 5; ++p5) { pV[pbase+p5] = lv[p5]; pP[pbase+p5] = lp[p5]; }
            }
        }
        __syncthreads();
    }
}

// fused merge + edge MLP, 4 threads per src point (j-loop split in 32-chunks,
// pairwise shfl_xor sum — summation-order change only, within edge tolerance).
__global__ __launch_bounds__(256) void k_edge(const float* __restrict__ X,
        const float* __restrict__ W1, const float* __restrict__ b1,
        const float* __restrict__ W2, const float* __restrict__ b2,
        const float* __restrict__ pV, const int* __restrict__ pP,
        const int* __restrict__ sortedIdx, float* __restrict__ out) {
    __shared__ float w1t[128*36];
    __shared__ float b1l[128];
    __shared__ float w2l[128];
    const int tid = threadIdx.x;
    for (int idx = tid; idx < 33*128; idx += 256) {
        int f = idx >> 7, j = idx & 127;
        w1t[j*36 + f] = W1[idx];
    }
    if (tid < 128) { b1l[tid] = b1[tid]; w2l[tid] = W2[tid]; }
    __syncthreads();
    int rid4 = blockIdx.x*256 + tid;
    if (rid4 >= NGRP*BINSZ*4) return;
    const int rid = rid4 >> 2, quarter = rid4 & 3;
    const int grp = rid / BINSZ;
    const int rowLocal = rid - grp*BINSZ;
    const int b = grp / NBINS, g = grp - b*NBINS;
    // ---- merge 4 ch-partials (duplicated across the 4 quarters; deterministic) ----
    float lv[5]; int lp[5];
    {
        int pbase = (grp*4*PROWS + rowLocal)*5;
        #pragma unroll
        for (int j = 0; j < 5; ++j) { lv[j] = pV[pbase+j]; lp[j] = pP[pbase+j]; }
    }
    #pragma unroll
    for (int chh = 1; chh < 4; ++chh) {
        int pbase = ((grp*4 + chh)*PROWS + rowLocal)*5;
        #pragma unroll
        for (int j = 0; j < 5; ++j) {
            float v = pV[pbase+j]; int p = pP[pbase+j];
            INS_TIE(lv, lp, v, p);
        }
    }
    const int* sIdx = sortedIdx + b*NPTS + g*BINSZ;
    const int src = sIdx[rowLocal];
    int dd[5]; float vv[5];
    #pragma unroll
    for (int j = 0; j < 5; ++j) {
        dd[j] = sIdx[lp[j]];
        vv[j] = 1.f/(1.f + expf(-lv[j]));
    }
    #define CSWAP(i,j) { if (dd[i] > dd[j]) { int td=dd[i];dd[i]=dd[j];dd[j]=td; \
                         float tf=vv[i];vv[i]=vv[j];vv[j]=tf; } }
    CSWAP(0,1) CSWAP(3,4) CSWAP(2,4) CSWAP(2,3) CSWAP(1,4)
    CSWAP(0,3) CSWAP(0,2) CSWAP(1,3) CSWAP(1,2)
    #undef CSWAP
    const int base = b*EDGES_PER_BATCH + src*5;
    if (quarter == 0) {
        #pragma unroll
        for (int e = 0; e < 5; ++e) {
            out[EDGE_TOT   + base + e] = (float)src;
            out[2*EDGE_TOT + base + e] = (float)dd[e];
        }
    }
    // ---- edge MLP over j-range [quarter*32, quarter*32+32) ----
    float4 xs[4];
    {
        const float4* xp = (const float4*)(X + ((size_t)b*NPTS + src)*NFEAT);
        #pragma unroll
        for (int q = 0; q < 4; ++q) xs[q] = xp[q];
    }
    float4 xd[5][4];
    #pragma unroll
    for (int e = 0; e < 5; ++e) {
        const float4* xp = (const float4*)(X + ((size_t)b*NPTS + dd[e])*NFEAT);
        #pragma unroll
        for (int q = 0; q < 4; ++q) xd[e][q] = xp[q];
    }
    float acc[5] = {0.f,0.f,0.f,0.f,0.f};
    const int jEnd = quarter*32 + 32;
    for (int j = quarter*32; j < jEnd; ++j) {
        const float* wr = &w1t[j*36];
        float4 ws0 = ((const float4*)wr)[0];
        float4 ws1 = ((const float4*)wr)[1];
        float4 ws2 = ((const float4*)wr)[2];
        float4 ws3 = ((const float4*)wr)[3];
        float4 u0  = ((const float4*)(wr+16))[0];
        float4 u1  = ((const float4*)(wr+16))[1];
        float4 u2  = ((const float4*)(wr+16))[2];
        float4 u3  = ((const float4*)(wr+16))[3];
        float w32 = wr[32];
        float w2j = w2l[j];
        float sh = b1l[j]
            + xs[0].x*ws0.x + xs[0].y*ws0.y + xs[0].z*ws0.z + xs[0].w*ws0.w
            + xs[1].x*ws1.x + xs[1].y*ws1.y + xs[1].z*ws1.z + xs[1].w*ws1.w
            + xs[2].x*ws2.x + xs[2].y*ws2.y + xs[2].z*ws2.z + xs[2].w*ws2.w
            + xs[3].x*ws3.x + xs[3].y*ws3.y + xs[3].z*ws3.z + xs[3].w*ws3.w;
        #pragma unroll
        for (int e = 0; e < 5; ++e) {
            float h = sh
                + xd[e][0].x*u0.x + xd[e][0].y*u0.y + xd[e][0].z*u0.z + xd[e][0].w*u0.w
                + xd[e][1].x*u1.x + xd[e][1].y*u1.y + xd[e][1].z*u1.z + xd[e][1].w*u1.w
                + xd[e][2].x*u2.x + xd[e][2].y*u2.y + xd[e][2].z*u2.z + xd[e][2].w*u2.w
                + xd[e][3].x*u3.x + xd[e][3].y*u3.y + xd[e][3].z*u3.z + xd[e][3].w*u3.w;
            h += vv[e]*w32;
            h = (h > 0.f) ? h : expm1f(h);
            acc[e] += h * w2j;
        }
    }
    // pairwise reduce across the 4 quarters: ((q0+q1)+(q2+q3))
    #pragma unroll
    for (int e = 0; e < 5; ++e) {
        acc[e] += __shfl_xor(acc[e], 1, 64);
        acc[e] += __shfl_xor(acc[e], 2, 64);
    }
    if (quarter != 0) return;
    float b2v = b2[0];
    #pragma unroll
    for (int e = 0; e < 5; ++e) {
        out[base + e] = 1.f/(1.f + expf(-(acc[e] + b2v)));
    }
}

extern "C" void kernel_launch(void* const* d_in, const int* in_sizes, int n_in,
                              void* d_out, int out_size, void* d_ws, size_t ws_size,
                              hipStream_t stream) {
    const float* X   = (const float*)d_in[0];
    const float* We1 = (const float*)d_in[1];
    const float* be1 = (const float*)d_in[2];
    const float* We2 = (const float*)d_in[3];
    const float* be2 = (const float*)d_in[4];
    const float* Wd1 = (const float*)d_in[5];
    const float* bd1 = (const float*)d_in[6];
    const float* Wd2 = (const float*)d_in[7];
    const float* bd2 = (const float*)d_in[8];
    const float* R   = (const float*)d_in[9];
    float* out = (float*)d_out;

    // workspace layout (~54 MB, unchanged footprint):
    // P[row][256] = [H|L] occupies exactly the old He+Le slab.
    u16* Pw         = (u16*)d_ws;                          // 80000*256 u16
    int*   binIdx   = (int*)(Pw + (size_t)TOTPTS*256);     // 80000
    int*   sortedIdx= binIdx + TOTPTS;                     // 80000
    int*   hist     = sortedIdx + TOTPTS;                  // 160
    float* pV       = (float*)(hist + NBATCH*NBINS);       // 160*4*512*5
    int*   pP       = (int*)(pV + (size_t)NGRP*4*PROWS*5); // 160*4*512*5

    k_enc  <<<TOTPTS/32, 256, 0, stream>>>(X, We1, be1, We2, be2, Pw, hist);
    k_bins <<<(TOTPTS+255)/256, 256, 0, stream>>>(Pw, R, binIdx, hist);
    k_sort <<<NBATCH*NBINS, 256, 0, stream>>>(binIdx, hist, sortedIdx);
    k_gram <<<NGRP*16, 256, 0, stream>>>(Pw, sortedIdx, pV, pP);
    k_edge <<<(NGRP*BINSZ*4+255)/256, 256, 0, stream>>>(X, Wd1, bd1, Wd2, bd2,
                                                        pV, pP, sortedIdx, out);
}

// Round 3
// 467.628 us; speedup vs baseline: 1.3977x; 1.0603x over previous
//
#include <hip/hip_runtime.h>
#include <cmath>

#define NPTS 10000
#define NBATCH 8
#define NFEAT 16
#define DDIM 128
#define NBINS 20
#define BINSZ 500
#define KSEL 5
#define EDGES_PER_BATCH (NPTS*KSEL)        // 50000
#define EDGE_TOT (NBATCH*EDGES_PER_BATCH)  // 400000
#define TOTPTS (NBATCH*NPTS)               // 80000
#define NGRP (NBATCH*NBINS)                // 160
#define PROWS 512                          // padded rows per (grp,ch) partial slab

typedef _Float16 f16x8 __attribute__((ext_vector_type(8)));
typedef float f32x4 __attribute__((ext_vector_type(4)));
typedef unsigned short u16;
typedef unsigned int u32;

// fp32 -> (h, l) with x ~= h + l * 2^-12.  h forced to 0 below fp16 min-normal
// so every stored value is normal/zero (no MFMA denormal-flush exposure).
static __device__ __forceinline__ void split_f16(float v, u16& hu, u16& lu) {
    _Float16 h = (_Float16)v;
    float hf = (float)h;
    if (fabsf(v) < 6.103515625e-05f) { h = (_Float16)0.0f; hf = 0.0f; }
    _Float16 l = (_Float16)((v - hf) * 4096.0f);
    hu = __builtin_bit_cast(u16, h);
    lu = __builtin_bit_cast(u16, l);
}

static __device__ __forceinline__ float f16bits(u16 u) {
    return (float)__builtin_bit_cast(_Float16, u);
}

// enc = ELU(X@W1+b1)@W2+b2, stored as P[row][256] = [H(128) | L(128)] f16.
// Block 0 also zeroes the bin histogram (k_bins runs after k_enc completes).
__global__ __launch_bounds__(256) void k_enc(const float* __restrict__ X,
        const float* __restrict__ W1, const float* __restrict__ b1,
        const float* __restrict__ W2, const float* __restrict__ b2,
        u16* __restrict__ P, int* __restrict__ hist) {
    __shared__ float hT[128*36];
    const int tid = threadIdx.x;
    const int P0 = blockIdx.x * 32;
    if (blockIdx.x == 0 && tid < NBATCH*NBINS) hist[tid] = 0;
    #pragma unroll
    for (int i = 0; i < 16; ++i) {
        int idx = i*256 + tid;
        int p = idx >> 7;
        int j = idx & 127;
        const float* xr = X + (size_t)(P0 + p)*NFEAT;
        float h = b1[j];
        #pragma unroll
        for (int f = 0; f < 16; ++f) h += xr[f] * W1[f*128 + j];
        h = (h > 0.f) ? h : expm1f(h);
        hT[j*36 + p] = h;
    }
    __syncthreads();
    const int jt = tid & 31, pt = tid >> 5;
    const int j0 = jt*4, p0 = pt*4;
    float acc[4][4];
    #pragma unroll
    for (int ep = 0; ep < 4; ++ep)
        #pragma unroll
        for (int ej = 0; ej < 4; ++ej) acc[ep][ej] = b2[j0+ej];
    for (int k = 0; k < 128; ++k) {
        float4 hv = *(const float4*)&hT[k*36 + p0];
        float4 wv = *(const float4*)&W2[k*128 + j0];
        float hvv[4] = {hv.x,hv.y,hv.z,hv.w};
        float wvv[4] = {wv.x,wv.y,wv.z,wv.w};
        #pragma unroll
        for (int ep = 0; ep < 4; ++ep)
            #pragma unroll
            for (int ej = 0; ej < 4; ++ej) acc[ep][ej] += hvv[ep]*wvv[ej];
    }
    #pragma unroll
    for (int ep = 0; ep < 4; ++ep) {
        u16 hs[4], ls[4];
        #pragma unroll
        for (int ej = 0; ej < 4; ++ej) split_f16(acc[ep][ej], hs[ej], ls[ej]);
        size_t ro = (size_t)(P0+p0+ep)*256 + j0;
        uint2 hv2, lv2;
        hv2.x = (u32)hs[0] | ((u32)hs[1]<<16); hv2.y = (u32)hs[2] | ((u32)hs[3]<<16);
        lv2.x = (u32)ls[0] | ((u32)ls[1]<<16); lv2.y = (u32)ls[2] | ((u32)ls[3]<<16);
        *(uint2*)&P[ro]       = hv2;
        *(uint2*)&P[ro + 128] = lv2;
    }
}

// mul = enc @ R[:, :10]; bin = argmax([mul, -mul]) first-max-wins; histogram.
// enc reconstructed as h + l*2^-12 (error ~2^-22 rel, below bin-argmax gaps).
__global__ __launch_bounds__(256) void k_bins(const u16* __restrict__ P,
        const float* __restrict__ R,
        int* __restrict__ binIdx, int* __restrict__ hist) {
    __shared__ float Rl[128*10];
    const int tid = threadIdx.x;
    for (int idx = tid; idx < 1280; idx += 256) {
        int d = idx / 10, i = idx % 10;
        Rl[idx] = R[d*100 + i];
    }
    __syncthreads();
    int gp = blockIdx.x*256 + tid;
    if (gp >= TOTPTS) return;
    float acc[10];
    #pragma unroll
    for (int i = 0; i < 10; ++i) acc[i] = 0.f;
    const uint4* hr = (const uint4*)(P + (size_t)gp*256);
    const uint4* lr = (const uint4*)(P + (size_t)gp*256 + 128);
    const float sc = 2.44140625e-4f;
    for (int c = 0; c < 16; ++c) {
        uint4 hv = hr[c], lv = lr[c];
        float x[8];
        x[0] = f16bits((u16)(hv.x & 0xffff)) + f16bits((u16)(lv.x & 0xffff))*sc;
        x[1] = f16bits((u16)(hv.x >> 16))    + f16bits((u16)(lv.x >> 16))*sc;
        x[2] = f16bits((u16)(hv.y & 0xffff)) + f16bits((u16)(lv.y & 0xffff))*sc;
        x[3] = f16bits((u16)(hv.y >> 16))    + f16bits((u16)(lv.y >> 16))*sc;
        x[4] = f16bits((u16)(hv.z & 0xffff)) + f16bits((u16)(lv.z & 0xffff))*sc;
        x[5] = f16bits((u16)(hv.z >> 16))    + f16bits((u16)(lv.z >> 16))*sc;
        x[6] = f16bits((u16)(hv.w & 0xffff)) + f16bits((u16)(lv.w & 0xffff))*sc;
        x[7] = f16bits((u16)(hv.w >> 16))    + f16bits((u16)(lv.w >> 16))*sc;
        #pragma unroll
        for (int e = 0; e < 8; ++e) {
            const float* rr = &Rl[(c*8+e)*10];
            #pragma unroll
            for (int i = 0; i < 10; ++i) acc[i] += x[e]*rr[i];
        }
    }
    float best = acc[0]; int bi = 0;
    #pragma unroll
    for (int i = 1; i < 10; ++i) if (acc[i] > best) { best = acc[i]; bi = i; }
    #pragma unroll
    for (int i = 0; i < 10; ++i) { float v = -acc[i]; if (v > best) { best = v; bi = 10+i; } }
    binIdx[gp] = bi;
    atomicAdd(&hist[(gp/NPTS)*NBINS + bi], 1);
}

// stable counting-sort scatter: one block per (batch,bin)
__global__ __launch_bounds__(256) void k_sort(const int* __restrict__ binIdx,
        const int* __restrict__ hist, int* __restrict__ sortedIdx) {
    const int b = blockIdx.x / NBINS;
    const int bin = blockIdx.x % NBINS;
    const int tid = threadIdx.x;
    __shared__ int wtot[4];
    int off = 0;
    for (int k = 0; k < bin; ++k) off += hist[b*NBINS + k];
    const int* bptr = binIdx + b*NPTS;
    int* sptr = sortedIdx + b*NPTS;
    const int lane = tid & 63, wid = tid >> 6;
    for (int c = 0; c < 40; ++c) {
        int i = c*256 + tid;
        bool pred = (i < NPTS) && (bptr[i] == bin);
        unsigned long long mask = __ballot(pred);
        int rank = __popcll(mask & ((1ULL << lane) - 1ULL));
        if (lane == 0) wtot[wid] = __popcll(mask);
        __syncthreads();
        int prefix = 0;
        #pragma unroll
        for (int w = 0; w < 4; ++w) prefix += (w < wid) ? wtot[w] : 0;
        int total = wtot[0]+wtot[1]+wtot[2]+wtot[3];
        if (pred) sptr[off + prefix + rank] = i;
        off += total;
        __syncthreads();
    }
}

// tie-aware better-than: (v desc, p asc) — exact lax.top_k semantics
#define BT(va,pa,vb,pb) (((va) > (vb)) || (((va) == (vb)) && ((pa) < (pb))))
#define INS_TIE(VV,PP,v,p) do { \
  if (BT(v,p,VV[4],PP[4])) { \
    if (BT(v,p,VV[3],PP[3])) { VV[4]=VV[3]; PP[4]=PP[3]; \
      if (BT(v,p,VV[2],PP[2])) { VV[3]=VV[2]; PP[3]=PP[2]; \
        if (BT(v,p,VV[1],PP[1])) { VV[2]=VV[1]; PP[2]=PP[1]; \
          if (BT(v,p,VV[0],PP[0])) { VV[1]=VV[0]; PP[1]=PP[0]; VV[0]=(v); PP[0]=(p); } \
          else { VV[1]=(v); PP[1]=(p); } } \
        else { VV[2]=(v); PP[2]=(p); } } \
      else { VV[3]=(v); PP[3]=(p); } } \
    else { VV[4]=(v); PP[4]=(p); } } } while(0)

// Gram via f16 MFMA, single accumulator per tile:
//   acc = H_a·L_b^T + L_a·H_b^T + (64H_a)·(64H_b)^T ;  S = acc·2^-12
// (bit-identical products to the round-1/2 passing formula).
// v3 change: B-fragments staged cooperatively into LDS once per k-step
// (contiguous 64B/thread gathers — whole cache lines, no per-wave redundancy),
// fragments then read via ds_read_b128 from a stride-40(hw) layout whose
// bank-group map (5*l15 + l4) mod 8 is uniform (conflict-free at b128 floor).
// A-fragments remain direct scattered gathers (4 loads/ks/wave).
// Bs is UNIONED with the epilogue T tile -> LDS stays 35.8 KB, 4 blocks/CU.
__global__ __launch_bounds__(256, 3) void k_gram(const u16* __restrict__ P,
        const int* __restrict__ sortedIdx, float* __restrict__ pV, int* __restrict__ pP) {
    __shared__ int gIdx[512];
    __shared__ __align__(16) union ShU {
        struct { u16 H[128][40]; u16 L[128][40]; } bs;   // 20480 B
        float T[64][132];                                // 33792 B
    } sh;
    const int tid = threadIdx.x;
    const int unit = blockIdx.x / 160;      // rowTile*4 + ch
    const int grp  = blockIdx.x - unit*160;
    const int rowTile = unit >> 2, ch = unit & 3;
    const int b = grp / NBINS, g = grp - b*NBINS;
    for (int i = tid; i < 512; i += 256) gIdx[i] = sortedIdx[b*NPTS + g*500 + min(i, 499)];
    __syncthreads();

    const int w    = tid >> 6;              // wave 0..3: rows w*32..w*32+31
    const int lane = tid & 63;
    const int l15  = lane & 15, l4 = lane >> 4;
    const int rowBase = rowTile * 128;

    const size_t ebase = (size_t)b * NPTS * 256;   // halfwords
    const u16* PB = P + ebase;
    const u16* pA0 = PB + (size_t)gIdx[rowBase + w*32 +      l15]*256 + l4*8;
    const u16* pA1 = PB + (size_t)gIdx[rowBase + w*32 + 16 + l15]*256 + l4*8;

    // stager role: thread t copies the 64B ks-chunk of col (t>>1), part (t&1)
    const int scol = tid >> 1, spart = tid & 1;
    const u16* pS = PB + (size_t)gIdx[ch*128 + scol]*256 + spart*128;
    u16* dS = spart ? &sh.bs.L[scol][0] : &sh.bs.H[scol][0];

    f32x4 acc[2][8];
    const f32x4 z4 = {0.f, 0.f, 0.f, 0.f};
    #pragma unroll
    for (int rf = 0; rf < 2; ++rf)
        #pragma unroll
        for (int cf = 0; cf < 8; ++cf) acc[rf][cf] = z4;

    const _Float16 c64 = (_Float16)64.0f;
    #pragma unroll 1
    for (int ks = 0; ks < 4; ++ks) {
        __syncthreads();                    // prior k-step's LDS reads done
        {   // stage B: 32 hw (64B) contiguous per thread, 4x ds_write_b128
            const uint4* s = (const uint4*)(pS + ks*32);
            uint4 v0 = s[0], v1 = s[1], v2 = s[2], v3 = s[3];
            uint4* d = (uint4*)dS;
            d[0] = v0; d[1] = v1; d[2] = v2; d[3] = v3;
        }
        const int oH = ks*32, oL = 128 + ks*32;
        const f16x8 aH0 = *(const f16x8*)(pA0 + oH);
        const f16x8 aL0 = *(const f16x8*)(pA0 + oL);
        const f16x8 aH1 = *(const f16x8*)(pA1 + oH);
        const f16x8 aL1 = *(const f16x8*)(pA1 + oL);
        const f16x8 aS0 = aH0 * c64;
        const f16x8 aS1 = aH1 * c64;
        __syncthreads();                    // staged data visible
        #pragma unroll
        for (int cf = 0; cf < 8; ++cf) {
            const int col = cf*16 + l15;
            const f16x8 bH = *(const f16x8*)&sh.bs.H[col][l4*8];
            const f16x8 bL = *(const f16x8*)&sh.bs.L[col][l4*8];
            const f16x8 bS = bH * c64;
            acc[0][cf] = __builtin_amdgcn_mfma_f32_16x16x32_f16(aH0, bL, acc[0][cf], 0, 0, 0);
            acc[1][cf] = __builtin_amdgcn_mfma_f32_16x16x32_f16(aH1, bL, acc[1][cf], 0, 0, 0);
            acc[0][cf] = __builtin_amdgcn_mfma_f32_16x16x32_f16(aL0, bH, acc[0][cf], 0, 0, 0);
            acc[1][cf] = __builtin_amdgcn_mfma_f32_16x16x32_f16(aL1, bH, acc[1][cf], 0, 0, 0);
            acc[0][cf] = __builtin_amdgcn_mfma_f32_16x16x32_f16(aS0, bS, acc[0][cf], 0, 0, 0);
            acc[1][cf] = __builtin_amdgcn_mfma_f32_16x16x32_f16(aS1, bS, acc[1][cf], 0, 0, 0);
        }
    }
    __syncthreads();                        // k-loop LDS reads done; reuse as T

    // ---- epilogue: per rf-half, LDS transpose then 4-thread/row top-5 ----
    const float sc = 2.44140625e-4f;        // 2^-12
    const int rT = tid >> 2;                // 0..63: T-row this thread reduces
    const int q  = tid & 3;                 // quarter: cols q*32..q*32+31
    const int nI = (ch == 3 && q == 3) ? 20 : 32;   // cols valid (<500) this quarter
    #pragma unroll
    for (int rf = 0; rf < 2; ++rf) {
        #pragma unroll
        for (int cf = 0; cf < 8; ++cf) {
            const int col = cf*16 + l15;
            const int r0  = w*16 + l4*4;
            #pragma unroll
            for (int j = 0; j < 4; ++j) sh.T[r0+j][col] = acc[rf][cf][j] * sc;
        }
        __syncthreads();
        float lv[5]; int lp[5];
        #pragma unroll
        for (int p5 = 0; p5 < 5; ++p5) { lv[p5] = -3.4e38f; lp[p5] = 0x7fffffff; }
        const float* Tr = &sh.T[rT][q*32];
        #pragma unroll
        for (int t = 0; t < 8; ++t) {
            const int c4 = (t + q*2) & 7;   // bank-rotated visit order
            float4 v4 = *(const float4*)&Tr[c4*4];
            float vv4[4] = {v4.x, v4.y, v4.z, v4.w};
            #pragma unroll
            for (int e = 0; e < 4; ++e) {
                const int i = c4*4 + e;
                if (i < nI) INS_TIE(lv, lp, vv4[e], ch*128 + q*32 + i);
            }
        }
        #pragma unroll
        for (int m = 1; m < 4; m <<= 1) {
            float qv[5]; int qp[5];
            #pragma unroll
            for (int p5 = 0; p5 < 5; ++p5) {
                qv[p5] = __shfl_xor(lv[p5], m, 64);
                qp[p5] = __shfl_xor(lp[p5], m, 64);
            }
            #pragma unroll
            for (int p5 = 0; p5 < 5; ++p5) INS_TIE(lv, lp, qv[p5], qp[p5]);
        }
        if (q == 0) {
            const int rpos = rowBase + (rT>>4)*32 + rf*16 + (rT&15);
            if (rpos < 500) {
                const int pbase = ((grp*4 + ch)*PROWS + rpos)*5;
                #pragma unroll
                for (int p5 = 0; p5 < 5; ++p5) { pV[pbase+p5] = lv[p5]; pP[pbase+p5] = lp[p5]; }
            }
        }
        __syncthreads();
    }
}

// fused merge + edge MLP, 4 threads per src point (j-loop split in 32-chunks,
// pairwise shfl_xor sum — summation-order change only, within edge tolerance).
__global__ __launch_bounds__(256) void k_edge(const float* __restrict__ X,
        const float* __restrict__ W1, const float* __restrict__ b1,
        const float* __restrict__ W2, const float* __restrict__ b2,
        const float* __restrict__ pV, const int* __restrict__ pP,
        const int* __restrict__ sortedIdx, float* __restrict__ out) {
    __shared__ float w1t[128*36];
    __shared__ float b1l[128];
    __shared__ float w2l[128];
    const int tid = threadIdx.x;
    for (int idx = tid; idx < 33*128; idx += 256) {
        int f = idx >> 7, j = idx & 127;
        w1t[j*36 + f] = W1[idx];
    }
    if (tid < 128) { b1l[tid] = b1[tid]; w2l[tid] = W2[tid]; }
    __syncthreads();
    int rid4 = blockIdx.x*256 + tid;
    if (rid4 >= NGRP*BINSZ*4) return;
    const int rid = rid4 >> 2, quarter = rid4 & 3;
    const int grp = rid / BINSZ;
    const int rowLocal = rid - grp*BINSZ;
    const int b = grp / NBINS, g = grp - b*NBINS;
    // ---- merge 4 ch-partials (duplicated across the 4 quarters; deterministic) ----
    float lv[5]; int lp[5];
    {
        int pbase = (grp*4*PROWS + rowLocal)*5;
        #pragma unroll
        for (int j = 0; j < 5; ++j) { lv[j] = pV[pbase+j]; lp[j] = pP[pbase+j]; }
    }
    #pragma unroll
    for (int chh = 1; chh < 4; ++chh) {
        int pbase = ((grp*4 + chh)*PROWS + rowLocal)*5;
        #pragma unroll
        for (int j = 0; j < 5; ++j) {
            float v = pV[pbase+j]; int p = pP[pbase+j];
            INS_TIE(lv, lp, v, p);
        }
    }
    const int* sIdx = sortedIdx + b*NPTS + g*BINSZ;
    const int src = sIdx[rowLocal];
    int dd[5]; float vv[5];
    #pragma unroll
    for (int j = 0; j < 5; ++j) {
        dd[j] = sIdx[lp[j]];
        vv[j] = 1.f/(1.f + expf(-lv[j]));
    }
    #define CSWAP(i,j) { if (dd[i] > dd[j]) { int td=dd[i];dd[i]=dd[j];dd[j]=td; \
                         float tf=vv[i];vv[i]=vv[j];vv[j]=tf; } }
    CSWAP(0,1) CSWAP(3,4) CSWAP(2,4) CSWAP(2,3) CSWAP(1,4)
    CSWAP(0,3) CSWAP(0,2) CSWAP(1,3) CSWAP(1,2)
    #undef CSWAP
    const int base = b*EDGES_PER_BATCH + src*5;
    if (quarter == 0) {
        #pragma unroll
        for (int e = 0; e < 5; ++e) {
            out[EDGE_TOT   + base + e] = (float)src;
            out[2*EDGE_TOT + base + e] = (float)dd[e];
        }
    }
    // ---- edge MLP over j-range [quarter*32, quarter*32+32) ----
    float4 xs[4];
    {
        const float4* xp = (const float4*)(X + ((size_t)b*NPTS + src)*NFEAT);
        #pragma unroll
        for (int q = 0; q < 4; ++q) xs[q] = xp[q];
    }
    float4 xd[5][4];
    #pragma unroll
    for (int e = 0; e < 5; ++e) {
        const float4* xp = (const float4*)(X + ((size_t)b*NPTS + dd[e])*NFEAT);
        #pragma unroll
        for (int q = 0; q < 4; ++q) xd[e][q] = xp[q];
    }
    float acc[5] = {0.f,0.f,0.f,0.f,0.f};
    const int jEnd = quarter*32 + 32;
    for (int j = quarter*32; j < jEnd; ++j) {
        const float* wr = &w1t[j*36];
        float4 ws0 = ((const float4*)wr)[0];
        float4 ws1 = ((const float4*)wr)[1];
        float4 ws2 = ((const float4*)wr)[2];
        float4 ws3 = ((const float4*)wr)[3];
        float4 u0  = ((const float4*)(wr+16))[0];
        float4 u1  = ((const float4*)(wr+16))[1];
        float4 u2  = ((const float4*)(wr+16))[2];
        float4 u3  = ((const float4*)(wr+16))[3];
        float w32 = wr[32];
        float w2j = w2l[j];
        float sh = b1l[j]
            + xs[0].x*ws0.x + xs[0].y*ws0.y + xs[0].z*ws0.z + xs[0].w*ws0.w
            + xs[1].x*ws1.x + xs[1].y*ws1.y + xs[1].z*ws1.z + xs[1].w*ws1.w
            + xs[2].x*ws2.x + xs[2].y*ws2.y + xs[2].z*ws2.z + xs[2].w*ws2.w
            + xs[3].x*ws3.x + xs[3].y*ws3.y + xs[3].z*ws3.z + xs[3].w*ws3.w;
        #pragma unroll
        for (int e = 0; e < 5; ++e) {
            float h = sh
                + xd[e][0].x*u0.x + xd[e][0].y*u0.y + xd[e][0].z*u0.z + xd[e][0].w*u0.w
                + xd[e][1].x*u1.x + xd[e][1].y*u1.y + xd[e][1].z*u1.z + xd[e][1].w*u1.w
                + xd[e][2].x*u2.x + xd[e][2].y*u2.y + xd[e][2].z*u2.z + xd[e][2].w*u2.w
                + xd[e][3].x*u3.x + xd[e][3].y*u3.y + xd[e][3].z*u3.z + xd[e][3].w*u3.w;
            h += vv[e]*w32;
            h = (h > 0.f) ? h : expm1f(h);
            acc[e] += h * w2j;
        }
    }
    // pairwise reduce across the 4 quarters: ((q0+q1)+(q2+q3))
    #pragma unroll
    for (int e = 0; e < 5; ++e) {
        acc[e] += __shfl_xor(acc[e], 1, 64);
        acc[e] += __shfl_xor(acc[e], 2, 64);
    }
    if (quarter != 0) return;
    float b2v = b2[0];
    #pragma unroll
    for (int e = 0; e < 5; ++e) {
        out[base + e] = 1.f/(1.f + expf(-(acc[e] + b2v)));
    }
}

extern "C" void kernel_launch(void* const* d_in, const int* in_sizes, int n_in,
                              void* d_out, int out_size, void* d_ws, size_t ws_size,
                              hipStream_t stream) {
    const float* X   = (const float*)d_in[0];
    const float* We1 = (const float*)d_in[1];
    const float* be1 = (const float*)d_in[2];
    const float* We2 = (const float*)d_in[3];
    const float* be2 = (const float*)d_in[4];
    const float* Wd1 = (const float*)d_in[5];
    const float* bd1 = (const float*)d_in[6];
    const float* Wd2 = (const float*)d_in[7];
    const float* bd2 = (const float*)d_in[8];
    const float* R   = (const float*)d_in[9];
    float* out = (float*)d_out;

    // workspace layout (~54 MB, unchanged footprint):
    // P[row][256] = [H|L] occupies exactly the old He+Le slab.
    u16* Pw         = (u16*)d_ws;                          // 80000*256 u16
    int*   binIdx   = (int*)(Pw + (size_t)TOTPTS*256);     // 80000
    int*   sortedIdx= binIdx + TOTPTS;                     // 80000
    int*   hist     = sortedIdx + TOTPTS;                  // 160
    float* pV       = (float*)(hist + NBATCH*NBINS);       // 160*4*512*5
    int*   pP       = (int*)(pV + (size_t)NGRP*4*PROWS*5); // 160*4*512*5

    k_enc  <<<TOTPTS/32, 256, 0, stream>>>(X, We1, be1, We2, be2, Pw, hist);
    k_bins <<<(TOTPTS+255)/256, 256, 0, stream>>>(Pw, R, binIdx, hist);
    k_sort <<<NBATCH*NBINS, 256, 0, stream>>>(binIdx, hist, sortedIdx);
    k_gram <<<NGRP*16, 256, 0, stream>>>(Pw, sortedIdx, pV, pP);
    k_edge <<<(NGRP*BINSZ*4+255)/256, 256, 0, stream>>>(X, Wd1, bd1, Wd2, bd2,
                                                        pV, pP, sortedIdx, out);
}

// Round 4
// 416.126 us; speedup vs baseline: 1.5707x; 1.1238x over previous
//
#include <hip/hip_runtime.h>
#include <cmath>

#define NPTS 10000
#define NBATCH 8
#define NFEAT 16
#define DDIM 128
#define NBINS 20
#define BINSZ 500
#define KSEL 5
#define EDGES_PER_BATCH (NPTS*KSEL)        // 50000
#define EDGE_TOT (NBATCH*EDGES_PER_BATCH)  // 400000
#define TOTPTS (NBATCH*NPTS)               // 80000
#define NGRP (NBATCH*NBINS)                // 160
#define PROWS 512                          // padded rows per (grp,ch) partial slab

typedef _Float16 f16x8 __attribute__((ext_vector_type(8)));
typedef float f32x4 __attribute__((ext_vector_type(4)));
typedef unsigned short u16;
typedef unsigned int u32;

// fp32 -> (Hs, D): Hs = 64*fp16(x), D = fp16((x - fp16(x)) * 64).
// Products then need no runtime scaling:
//   Hs*D = h*l, D*Hs = l*h, Hs*Hs = 4096*h*h  (same exact fp32 products as
//   the round-3 passing formula; S = acc * 2^-12).
// h forced to 0 below fp16 min-normal (no denormal-flush exposure on Hs);
// D flush only loses residuals < 9.5e-7 absolute — negligible.
static __device__ __forceinline__ void split_f16(float v, u16& hu, u16& du) {
    _Float16 h = (_Float16)v;
    float hf = (float)h;
    if (fabsf(v) < 6.103515625e-05f) { h = (_Float16)0.0f; hf = 0.0f; }
    _Float16 Hs = h * (_Float16)64.0f;              // exact (exponent shift)
    _Float16 D  = (_Float16)((v - hf) * 64.0f);
    hu = __builtin_bit_cast(u16, Hs);
    du = __builtin_bit_cast(u16, D);
}

static __device__ __forceinline__ float f16bits(u16 u) {
    return (float)__builtin_bit_cast(_Float16, u);
}

// enc = ELU(X@W1+b1)@W2+b2, stored as P[row][256] = [Hs(128) | D(128)] f16.
// Block 0 also zeroes the bin histogram (k_bins runs after k_enc completes).
__global__ __launch_bounds__(256) void k_enc(const float* __restrict__ X,
        const float* __restrict__ W1, const float* __restrict__ b1,
        const float* __restrict__ W2, const float* __restrict__ b2,
        u16* __restrict__ P, int* __restrict__ hist) {
    __shared__ float hT[128*36];
    const int tid = threadIdx.x;
    const int P0 = blockIdx.x * 32;
    if (blockIdx.x == 0 && tid < NBATCH*NBINS) hist[tid] = 0;
    #pragma unroll
    for (int i = 0; i < 16; ++i) {
        int idx = i*256 + tid;
        int p = idx >> 7;
        int j = idx & 127;
        const float* xr = X + (size_t)(P0 + p)*NFEAT;
        float h = b1[j];
        #pragma unroll
        for (int f = 0; f < 16; ++f) h += xr[f] * W1[f*128 + j];
        h = (h > 0.f) ? h : expm1f(h);
        hT[j*36 + p] = h;
    }
    __syncthreads();
    const int jt = tid & 31, pt = tid >> 5;
    const int j0 = jt*4, p0 = pt*4;
    float acc[4][4];
    #pragma unroll
    for (int ep = 0; ep < 4; ++ep)
        #pragma unroll
        for (int ej = 0; ej < 4; ++ej) acc[ep][ej] = b2[j0+ej];
    for (int k = 0; k < 128; ++k) {
        float4 hv = *(const float4*)&hT[k*36 + p0];
        float4 wv = *(const float4*)&W2[k*128 + j0];
        float hvv[4] = {hv.x,hv.y,hv.z,hv.w};
        float wvv[4] = {wv.x,wv.y,wv.z,wv.w};
        #pragma unroll
        for (int ep = 0; ep < 4; ++ep)
            #pragma unroll
            for (int ej = 0; ej < 4; ++ej) acc[ep][ej] += hvv[ep]*wvv[ej];
    }
    #pragma unroll
    for (int ep = 0; ep < 4; ++ep) {
        u16 hs[4], ds[4];
        #pragma unroll
        for (int ej = 0; ej < 4; ++ej) split_f16(acc[ep][ej], hs[ej], ds[ej]);
        size_t ro = (size_t)(P0+p0+ep)*256 + j0;
        uint2 hv2, dv2;
        hv2.x = (u32)hs[0] | ((u32)hs[1]<<16); hv2.y = (u32)hs[2] | ((u32)hs[3]<<16);
        dv2.x = (u32)ds[0] | ((u32)ds[1]<<16); dv2.y = (u32)ds[2] | ((u32)ds[3]<<16);
        *(uint2*)&P[ro]       = hv2;
        *(uint2*)&P[ro + 128] = dv2;
    }
}

// mul = enc @ R[:, :10]; bin = argmax([mul, -mul]) first-max-wins; histogram.
// Uses x' = Hs + D = 64*x — argmax is invariant to the positive scale.
__global__ __launch_bounds__(256) void k_bins(const u16* __restrict__ P,
        const float* __restrict__ R,
        int* __restrict__ binIdx, int* __restrict__ hist) {
    __shared__ float Rl[128*10];
    const int tid = threadIdx.x;
    for (int idx = tid; idx < 1280; idx += 256) {
        int d = idx / 10, i = idx % 10;
        Rl[idx] = R[d*100 + i];
    }
    __syncthreads();
    int gp = blockIdx.x*256 + tid;
    if (gp >= TOTPTS) return;
    float acc[10];
    #pragma unroll
    for (int i = 0; i < 10; ++i) acc[i] = 0.f;
    const uint4* hr = (const uint4*)(P + (size_t)gp*256);
    const uint4* lr = (const uint4*)(P + (size_t)gp*256 + 128);
    for (int c = 0; c < 16; ++c) {
        uint4 hv = hr[c], lv = lr[c];
        float x[8];
        x[0] = f16bits((u16)(hv.x & 0xffff)) + f16bits((u16)(lv.x & 0xffff));
        x[1] = f16bits((u16)(hv.x >> 16))    + f16bits((u16)(lv.x >> 16));
        x[2] = f16bits((u16)(hv.y & 0xffff)) + f16bits((u16)(lv.y & 0xffff));
        x[3] = f16bits((u16)(hv.y >> 16))    + f16bits((u16)(lv.y >> 16));
        x[4] = f16bits((u16)(hv.z & 0xffff)) + f16bits((u16)(lv.z & 0xffff));
        x[5] = f16bits((u16)(hv.z >> 16))    + f16bits((u16)(lv.z >> 16));
        x[6] = f16bits((u16)(hv.w & 0xffff)) + f16bits((u16)(lv.w & 0xffff));
        x[7] = f16bits((u16)(hv.w >> 16))    + f16bits((u16)(lv.w >> 16));
        #pragma unroll
        for (int e = 0; e < 8; ++e) {
            const float* rr = &Rl[(c*8+e)*10];
            #pragma unroll
            for (int i = 0; i < 10; ++i) acc[i] += x[e]*rr[i];
        }
    }
    float best = acc[0]; int bi = 0;
    #pragma unroll
    for (int i = 1; i < 10; ++i) if (acc[i] > best) { best = acc[i]; bi = i; }
    #pragma unroll
    for (int i = 0; i < 10; ++i) { float v = -acc[i]; if (v > best) { best = v; bi = 10+i; } }
    binIdx[gp] = bi;
    atomicAdd(&hist[(gp/NPTS)*NBINS + bi], 1);
}

// stable counting-sort scatter: one block per (batch,bin)
__global__ __launch_bounds__(256) void k_sort(const int* __restrict__ binIdx,
        const int* __restrict__ hist, int* __restrict__ sortedIdx) {
    const int b = blockIdx.x / NBINS;
    const int bin = blockIdx.x % NBINS;
    const int tid = threadIdx.x;
    __shared__ int wtot[4];
    int off = 0;
    for (int k = 0; k < bin; ++k) off += hist[b*NBINS + k];
    const int* bptr = binIdx + b*NPTS;
    int* sptr = sortedIdx + b*NPTS;
    const int lane = tid & 63, wid = tid >> 6;
    for (int c = 0; c < 40; ++c) {
        int i = c*256 + tid;
        bool pred = (i < NPTS) && (bptr[i] == bin);
        unsigned long long mask = __ballot(pred);
        int rank = __popcll(mask & ((1ULL << lane) - 1ULL));
        if (lane == 0) wtot[wid] = __popcll(mask);
        __syncthreads();
        int prefix = 0;
        #pragma unroll
        for (int w = 0; w < 4; ++w) prefix += (w < wid) ? wtot[w] : 0;
        int total = wtot[0]+wtot[1]+wtot[2]+wtot[3];
        if (pred) sptr[off + prefix + rank] = i;
        off += total;
        __syncthreads();
    }
}

// insert (v,p) into sorted-desc 5-list, strict > (candidates arrive ascending p)
#define INS_STRICT(VV,PP,v,p) do { \
  if ((v) > VV[4]) { \
    if ((v) > VV[3]) { VV[4]=VV[3]; PP[4]=PP[3]; \
      if ((v) > VV[2]) { VV[3]=VV[2]; PP[3]=PP[2]; \
        if ((v) > VV[1]) { VV[2]=VV[1]; PP[2]=PP[1]; \
          if ((v) > VV[0]) { VV[1]=VV[0]; PP[1]=PP[0]; VV[0]=(v); PP[0]=(p); } \
          else { VV[1]=(v); PP[1]=(p); } } \
        else { VV[2]=(v); PP[2]=(p); } } \
      else { VV[3]=(v); PP[3]=(p); } } \
    else { VV[4]=(v); PP[4]=(p); } } } while(0)

// tie-aware better-than: (v desc, p asc) — exact lax.top_k semantics
#define BT(va,pa,vb,pb) (((va) > (vb)) || (((va) == (vb)) && ((pa) < (pb))))
#define INS_TIE(VV,PP,v,p) do { \
  if (BT(v,p,VV[4],PP[4])) { \
    if (BT(v,p,VV[3],PP[3])) { VV[4]=VV[3]; PP[4]=PP[3]; \
      if (BT(v,p,VV[2],PP[2])) { VV[3]=VV[2]; PP[3]=PP[2]; \
        if (BT(v,p,VV[1],PP[1])) { VV[2]=VV[1]; PP[2]=PP[1]; \
          if (BT(v,p,VV[0],PP[0])) { VV[1]=VV[0]; PP[1]=PP[0]; VV[0]=(v); PP[0]=(p); } \
          else { VV[1]=(v); PP[1]=(p); } } \
        else { VV[2]=(v); PP[2]=(p); } } \
      else { VV[3]=(v); PP[3]=(p); } } \
    else { VV[4]=(v); PP[4]=(p); } } } while(0)

// Gram via f16 MFMA with pre-scaled split operands (zero runtime scaling):
//   acc = Hs_a·D_b + D_a·Hs_b + Hs_a·Hs_b ;  S = acc·2^-12
// (products bit-identical to the round-3 passing formula).
// v4 changes: (a) T14 async-stage split — next k-step's B-chunk prefetched
// into regs during the MFMA phase, so the ds_write at loop top hits in-flight
// data; (b) scale-free top-5 on raw acc (power-of-2 scale applied to the 5
// survivors only); (c) interleaved chunk order c4=4t+q -> ascending cpos
// (strict inserts) AND distinct bank-quads across the 4 same-row readers.
__global__ __launch_bounds__(256, 4) void k_gram(const u16* __restrict__ P,
        const int* __restrict__ sortedIdx, float* __restrict__ pV, int* __restrict__ pP) {
    __shared__ int gIdx[512];
    __shared__ __align__(16) union ShU {
        struct { u16 H[128][40]; u16 L[128][40]; } bs;   // 20480 B
        float T[64][132];                                // 33792 B
    } sh;
    const int tid = threadIdx.x;
    const int unit = blockIdx.x / 160;      // rowTile*4 + ch
    const int grp  = blockIdx.x - unit*160;
    const int rowTile = unit >> 2, ch = unit & 3;
    const int b = grp / NBINS, g = grp - b*NBINS;
    for (int i = tid; i < 512; i += 256) gIdx[i] = sortedIdx[b*NPTS + g*500 + min(i, 499)];
    __syncthreads();

    const int w    = tid >> 6;              // wave 0..3: rows w*32..w*32+31
    const int lane = tid & 63;
    const int l15  = lane & 15, l4 = lane >> 4;
    const int rowBase = rowTile * 128;

    const size_t ebase = (size_t)b * NPTS * 256;   // halfwords
    const u16* PB = P + ebase;
    const u16* pA0 = PB + (size_t)gIdx[rowBase + w*32 +      l15]*256 + l4*8;
    const u16* pA1 = PB + (size_t)gIdx[rowBase + w*32 + 16 + l15]*256 + l4*8;

    // stager role: thread t copies the 64B ks-chunk of col (t>>1), part (t&1)
    const int scol = tid >> 1, spart = tid & 1;
    const u16* pS = PB + (size_t)gIdx[ch*128 + scol]*256 + spart*128;
    u16* dS = spart ? &sh.bs.L[scol][0] : &sh.bs.H[scol][0];

    f32x4 acc[2][8];
    const f32x4 z4 = {0.f, 0.f, 0.f, 0.f};
    #pragma unroll
    for (int rf = 0; rf < 2; ++rf)
        #pragma unroll
        for (int cf = 0; cf < 8; ++cf) acc[rf][cf] = z4;

    // prologue: stage regs for ks=0
    uint4 s0, s1, s2, s3;
    { const uint4* s = (const uint4*)pS; s0 = s[0]; s1 = s[1]; s2 = s[2]; s3 = s[3]; }

    #pragma unroll
    for (int ks = 0; ks < 4; ++ks) {
        __syncthreads();                    // prior k-step's LDS reads done
        {   // write staged regs (data already in flight / in regs)
            uint4* d = (uint4*)dS;
            d[0] = s0; d[1] = s1; d[2] = s2; d[3] = s3;
        }
        if (ks < 3) {                       // prefetch next chunk: latency
            const uint4* s = (const uint4*)(pS + (ks+1)*32);   // hides under MFMA
            s0 = s[0]; s1 = s[1]; s2 = s[2]; s3 = s[3];
        }
        const int oH = ks*32, oD = 128 + ks*32;
        const f16x8 aH0 = *(const f16x8*)(pA0 + oH);
        const f16x8 aD0 = *(const f16x8*)(pA0 + oD);
        const f16x8 aH1 = *(const f16x8*)(pA1 + oH);
        const f16x8 aD1 = *(const f16x8*)(pA1 + oD);
        __syncthreads();                    // staged data visible
        #pragma unroll
        for (int cf = 0; cf < 8; ++cf) {
            const int col = cf*16 + l15;
            const f16x8 bH = *(const f16x8*)&sh.bs.H[col][l4*8];
            const f16x8 bD = *(const f16x8*)&sh.bs.L[col][l4*8];
            acc[0][cf] = __builtin_amdgcn_mfma_f32_16x16x32_f16(aH0, bD, acc[0][cf], 0, 0, 0);
            acc[1][cf] = __builtin_amdgcn_mfma_f32_16x16x32_f16(aH1, bD, acc[1][cf], 0, 0, 0);
            acc[0][cf] = __builtin_amdgcn_mfma_f32_16x16x32_f16(aD0, bH, acc[0][cf], 0, 0, 0);
            acc[1][cf] = __builtin_amdgcn_mfma_f32_16x16x32_f16(aD1, bH, acc[1][cf], 0, 0, 0);
            acc[0][cf] = __builtin_amdgcn_mfma_f32_16x16x32_f16(aH0, bH, acc[0][cf], 0, 0, 0);
            acc[1][cf] = __builtin_amdgcn_mfma_f32_16x16x32_f16(aH1, bH, acc[1][cf], 0, 0, 0);
        }
    }
    __syncthreads();                        // k-loop LDS reads done; reuse as T

    // ---- epilogue: per rf-half, LDS transpose then 4-thread/row top-5 ----
    const float sc = 2.44140625e-4f;        // 2^-12, applied to survivors only
    const int rT = tid >> 2;                // 0..63: T-row this thread reduces
    const int q  = tid & 3;                 // sub-chunks c4 = 4t+q (interleaved)
    const bool chk = (ch == 3);             // cols >= 116 invalid when ch==3
    #pragma unroll
    for (int rf = 0; rf < 2; ++rf) {
        #pragma unroll
        for (int cf = 0; cf < 8; ++cf) {
            const int col = cf*16 + l15;
            const int r0  = w*16 + l4*4;
            #pragma unroll
            for (int j = 0; j < 4; ++j) sh.T[r0+j][col] = acc[rf][cf][j];
        }
        __syncthreads();
        float lv[5]; int lp[5];
        #pragma unroll
        for (int p5 = 0; p5 < 5; ++p5) { lv[p5] = -3.4e38f; lp[p5] = 0x7fffffff; }
        const float* Tr = &sh.T[rT][0];
        #pragma unroll
        for (int t = 0; t < 8; ++t) {
            const int c4 = t*4 + q;         // ascending cpos; distinct bank-quads
            float4 v4 = *(const float4*)&Tr[c4*4];
            float vv4[4] = {v4.x, v4.y, v4.z, v4.w};
            #pragma unroll
            for (int e = 0; e < 4; ++e) {
                const int cloc = c4*4 + e;
                if (!chk || cloc < 116)     // 500-384: valid cols for ch==3
                    INS_STRICT(lv, lp, vv4[e], ch*128 + cloc);
            }
        }
        #pragma unroll
        for (int m = 1; m < 4; m <<= 1) {
            float qv[5]; int qp[5];
            #pragma unroll
            for (int p5 = 0; p5 < 5; ++p5) {
                qv[p5] = __shfl_xor(lv[p5], m, 64);
                qp[p5] = __shfl_xor(lp[p5], m, 64);
            }
            #pragma unroll
            for (int p5 = 0; p5 < 5; ++p5) INS_TIE(lv, lp, qv[p5], qp[p5]);
        }
        if (q == 0) {
            const int rpos = rowBase + (rT>>4)*32 + rf*16 + (rT&15);
            if (rpos < 500) {
                const int pbase = ((grp*4 + ch)*PROWS + rpos)*5;
                #pragma unroll
                for (int p5 = 0; p5 < 5; ++p5) { pV[pbase+p5] = lv[p5]*sc; pP[pbase+p5] = lp[p5]; }
            }
        }
        __syncthreads();
    }
}

// fused merge + edge MLP, 4 threads per src point (j-loop split in 32-chunks,
// pairwise shfl_xor sum — summation-order change only, within edge tolerance).
__global__ __launch_bounds__(256) void k_edge(const float* __restrict__ X,
        const float* __restrict__ W1, const float* __restrict__ b1,
        const float* __restrict__ W2, const float* __restrict__ b2,
        const float* __restrict__ pV, const int* __restrict__ pP,
        const int* __restrict__ sortedIdx, float* __restrict__ out) {
    __shared__ float w1t[128*36];
    __shared__ float b1l[128];
    __shared__ float w2l[128];
    const int tid = threadIdx.x;
    for (int idx = tid; idx < 33*128; idx += 256) {
        int f = idx >> 7, j = idx & 127;
        w1t[j*36 + f] = W1[idx];
    }
    if (tid < 128) { b1l[tid] = b1[tid]; w2l[tid] = W2[tid]; }
    __syncthreads();
    int rid4 = blockIdx.x*256 + tid;
    if (rid4 >= NGRP*BINSZ*4) return;
    const int rid = rid4 >> 2, quarter = rid4 & 3;
    const int grp = rid / BINSZ;
    const int rowLocal = rid - grp*BINSZ;
    const int b = grp / NBINS, g = grp - b*NBINS;
    // ---- merge 4 ch-partials (duplicated across the 4 quarters; deterministic) ----
    float lv[5]; int lp[5];
    {
        int pbase = (grp*4*PROWS + rowLocal)*5;
        #pragma unroll
        for (int j = 0; j < 5; ++j) { lv[j] = pV[pbase+j]; lp[j] = pP[pbase+j]; }
    }
    #pragma unroll
    for (int chh = 1; chh < 4; ++chh) {
        int pbase = ((grp*4 + chh)*PROWS + rowLocal)*5;
        #pragma unroll
        for (int j = 0; j < 5; ++j) {
            float v = pV[pbase+j]; int p = pP[pbase+j];
            INS_TIE(lv, lp, v, p);
        }
    }
    const int* sIdx = sortedIdx + b*NPTS + g*BINSZ;
    const int src = sIdx[rowLocal];
    int dd[5]; float vv[5];
    #pragma unroll
    for (int j = 0; j < 5; ++j) {
        dd[j] = sIdx[lp[j]];
        vv[j] = 1.f/(1.f + expf(-lv[j]));
    }
    #define CSWAP(i,j) { if (dd[i] > dd[j]) { int td=dd[i];dd[i]=dd[j];dd[j]=td; \
                         float tf=vv[i];vv[i]=vv[j];vv[j]=tf; } }
    CSWAP(0,1) CSWAP(3,4) CSWAP(2,4) CSWAP(2,3) CSWAP(1,4)
    CSWAP(0,3) CSWAP(0,2) CSWAP(1,3) CSWAP(1,2)
    #undef CSWAP
    const int base = b*EDGES_PER_BATCH + src*5;
    if (quarter == 0) {
        #pragma unroll
        for (int e = 0; e < 5; ++e) {
            out[EDGE_TOT   + base + e] = (float)src;
            out[2*EDGE_TOT + base + e] = (float)dd[e];
        }
    }
    // ---- edge MLP over j-range [quarter*32, quarter*32+32) ----
    float4 xs[4];
    {
        const float4* xp = (const float4*)(X + ((size_t)b*NPTS + src)*NFEAT);
        #pragma unroll
        for (int q = 0; q < 4; ++q) xs[q] = xp[q];
    }
    float4 xd[5][4];
    #pragma unroll
    for (int e = 0; e < 5; ++e) {
        const float4* xp = (const float4*)(X + ((size_t)b*NPTS + dd[e])*NFEAT);
        #pragma unroll
        for (int q = 0; q < 4; ++q) xd[e][q] = xp[q];
    }
    float acc[5] = {0.f,0.f,0.f,0.f,0.f};
    const int jEnd = quarter*32 + 32;
    for (int j = quarter*32; j < jEnd; ++j) {
        const float* wr = &w1t[j*36];
        float4 ws0 = ((const float4*)wr)[0];
        float4 ws1 = ((const float4*)wr)[1];
        float4 ws2 = ((const float4*)wr)[2];
        float4 ws3 = ((const float4*)wr)[3];
        float4 u0  = ((const float4*)(wr+16))[0];
        float4 u1  = ((const float4*)(wr+16))[1];
        float4 u2  = ((const float4*)(wr+16))[2];
        float4 u3  = ((const float4*)(wr+16))[3];
        float w32 = wr[32];
        float w2j = w2l[j];
        float sh = b1l[j]
            + xs[0].x*ws0.x + xs[0].y*ws0.y + xs[0].z*ws0.z + xs[0].w*ws0.w
            + xs[1].x*ws1.x + xs[1].y*ws1.y + xs[1].z*ws1.z + xs[1].w*ws1.w
            + xs[2].x*ws2.x + xs[2].y*ws2.y + xs[2].z*ws2.z + xs[2].w*ws2.w
            + xs[3].x*ws3.x + xs[3].y*ws3.y + xs[3].z*ws3.z + xs[3].w*ws3.w;
        #pragma unroll
        for (int e = 0; e < 5; ++e) {
            float h = sh
                + xd[e][0].x*u0.x + xd[e][0].y*u0.y + xd[e][0].z*u0.z + xd[e][0].w*u0.w
                + xd[e][1].x*u1.x + xd[e][1].y*u1.y + xd[e][1].z*u1.z + xd[e][1].w*u1.w
                + xd[e][2].x*u2.x + xd[e][2].y*u2.y + xd[e][2].z*u2.z + xd[e][2].w*u2.w
                + xd[e][3].x*u3.x + xd[e][3].y*u3.y + xd[e][3].z*u3.z + xd[e][3].w*u3.w;
            h += vv[e]*w32;
            h = (h > 0.f) ? h : expm1f(h);
            acc[e] += h * w2j;
        }
    }
    // pairwise reduce across the 4 quarters: ((q0+q1)+(q2+q3))
    #pragma unroll
    for (int e = 0; e < 5; ++e) {
        acc[e] += __shfl_xor(acc[e], 1, 64);
        acc[e] += __shfl_xor(acc[e], 2, 64);
    }
    if (quarter != 0) return;
    float b2v = b2[0];
    #pragma unroll
    for (int e = 0; e < 5; ++e) {
        out[base + e] = 1.f/(1.f + expf(-(acc[e] + b2v)));
    }
}

extern "C" void kernel_launch(void* const* d_in, const int* in_sizes, int n_in,
                              void* d_out, int out_size, void* d_ws, size_t ws_size,
                              hipStream_t stream) {
    const float* X   = (const float*)d_in[0];
    const float* We1 = (const float*)d_in[1];
    const float* be1 = (const float*)d_in[2];
    const float* We2 = (const float*)d_in[3];
    const float* be2 = (const float*)d_in[4];
    const float* Wd1 = (const float*)d_in[5];
    const float* bd1 = (const float*)d_in[6];
    const float* Wd2 = (const float*)d_in[7];
    const float* bd2 = (const float*)d_in[8];
    const float* R   = (const float*)d_in[9];
    float* out = (float*)d_out;

    // workspace layout (~54 MB, unchanged footprint):
    // P[row][256] = [Hs|D] occupies exactly the old slab.
    u16* Pw         = (u16*)d_ws;                          // 80000*256 u16
    int*   binIdx   = (int*)(Pw + (size_t)TOTPTS*256);     // 80000
    int*   sortedIdx= binIdx + TOTPTS;                     // 80000
    int*   hist     = sortedIdx + TOTPTS;                  // 160
    float* pV       = (float*)(hist + NBATCH*NBINS);       // 160*4*512*5
    int*   pP       = (int*)(pV + (size_t)NGRP*4*PROWS*5); // 160*4*512*5

    k_enc  <<<TOTPTS/32, 256, 0, stream>>>(X, We1, be1, We2, be2, Pw, hist);
    k_bins <<<(TOTPTS+255)/256, 256, 0, stream>>>(Pw, R, binIdx, hist);
    k_sort <<<NBATCH*NBINS, 256, 0, stream>>>(binIdx, hist, sortedIdx);
    k_gram <<<NGRP*16, 256, 0, stream>>>(Pw, sortedIdx, pV, pP);
    k_edge <<<(NGRP*BINSZ*4+255)/256, 256, 0, stream>>>(X, Wd1, bd1, Wd2, bd2,
                                                        pV, pP, sortedIdx, out);
}

// Round 5
// 403.569 us; speedup vs baseline: 1.6196x; 1.0311x over previous
//
#include <hip/hip_runtime.h>
#include <cmath>

#define NPTS 10000
#define NBATCH 8
#define NFEAT 16
#define DDIM 128
#define NBINS 20
#define BINSZ 500
#define KSEL 5
#define EDGES_PER_BATCH (NPTS*KSEL)        // 50000
#define EDGE_TOT (NBATCH*EDGES_PER_BATCH)  // 400000
#define TOTPTS (NBATCH*NPTS)               // 80000
#define NGRP (NBATCH*NBINS)                // 160
#define PROWS 512                          // padded rows per (grp,ch) partial slab

typedef _Float16 f16x8 __attribute__((ext_vector_type(8)));
typedef float f32x4 __attribute__((ext_vector_type(4)));
typedef unsigned short u16;
typedef unsigned int u32;

// fp32 -> (Hs, D): Hs = 64*fp16(x), D = fp16((x - fp16(x)) * 64).
// Products then need no runtime scaling:
//   Hs*D = h*l, D*Hs = l*h, Hs*Hs = 4096*h*h ;  S = acc * 2^-12.
static __device__ __forceinline__ void split_f16(float v, u16& hu, u16& du) {
    _Float16 h = (_Float16)v;
    float hf = (float)h;
    if (fabsf(v) < 6.103515625e-05f) { h = (_Float16)0.0f; hf = 0.0f; }
    _Float16 Hs = h * (_Float16)64.0f;              // exact (exponent shift)
    _Float16 D  = (_Float16)((v - hf) * 64.0f);
    hu = __builtin_bit_cast(u16, Hs);
    du = __builtin_bit_cast(u16, D);
}

static __device__ __forceinline__ float f16bits(u16 u) {
    return (float)__builtin_bit_cast(_Float16, u);
}

// enc = ELU(X@W1+b1)@W2+b2, stored as P[row][256] = [Hs(128) | D(128)] f16.
// Block 0 also zeroes the bin histogram (k_bins runs after k_enc completes).
__global__ __launch_bounds__(256) void k_enc(const float* __restrict__ X,
        const float* __restrict__ W1, const float* __restrict__ b1,
        const float* __restrict__ W2, const float* __restrict__ b2,
        u16* __restrict__ P, int* __restrict__ hist) {
    __shared__ float hT[128*36];
    const int tid = threadIdx.x;
    const int P0 = blockIdx.x * 32;
    if (blockIdx.x == 0 && tid < NBATCH*NBINS) hist[tid] = 0;
    #pragma unroll
    for (int i = 0; i < 16; ++i) {
        int idx = i*256 + tid;
        int p = idx >> 7;
        int j = idx & 127;
        const float* xr = X + (size_t)(P0 + p)*NFEAT;
        float h = b1[j];
        #pragma unroll
        for (int f = 0; f < 16; ++f) h += xr[f] * W1[f*128 + j];
        h = (h > 0.f) ? h : expm1f(h);
        hT[j*36 + p] = h;
    }
    __syncthreads();
    const int jt = tid & 31, pt = tid >> 5;
    const int j0 = jt*4, p0 = pt*4;
    float acc[4][4];
    #pragma unroll
    for (int ep = 0; ep < 4; ++ep)
        #pragma unroll
        for (int ej = 0; ej < 4; ++ej) acc[ep][ej] = b2[j0+ej];
    for (int k = 0; k < 128; ++k) {
        float4 hv = *(const float4*)&hT[k*36 + p0];
        float4 wv = *(const float4*)&W2[k*128 + j0];
        float hvv[4] = {hv.x,hv.y,hv.z,hv.w};
        float wvv[4] = {wv.x,wv.y,wv.z,wv.w};
        #pragma unroll
        for (int ep = 0; ep < 4; ++ep)
            #pragma unroll
            for (int ej = 0; ej < 4; ++ej) acc[ep][ej] += hvv[ep]*wvv[ej];
    }
    #pragma unroll
    for (int ep = 0; ep < 4; ++ep) {
        u16 hs[4], ds[4];
        #pragma unroll
        for (int ej = 0; ej < 4; ++ej) split_f16(acc[ep][ej], hs[ej], ds[ej]);
        size_t ro = (size_t)(P0+p0+ep)*256 + j0;
        uint2 hv2, dv2;
        hv2.x = (u32)hs[0] | ((u32)hs[1]<<16); hv2.y = (u32)hs[2] | ((u32)hs[3]<<16);
        dv2.x = (u32)ds[0] | ((u32)ds[1]<<16); dv2.y = (u32)ds[2] | ((u32)ds[3]<<16);
        *(uint2*)&P[ro]       = hv2;
        *(uint2*)&P[ro + 128] = dv2;
    }
}

// mul = enc @ R[:, :10]; bin = argmax([mul, -mul]) first-max-wins; histogram.
// Uses x' = Hs + D = 64*x — argmax invariant to the positive scale.
// v5: 4 threads/point (1250 blocks, ~20 waves/CU — was 313 blocks, latency-
// bound at 8% occupancy). Rl rows interleaved (d&31)*4+(d>>5) so the 4 segs
// of a wave read banks offset by 10 each — conflict-free (d-stride 32 would
// otherwise alias all 4 to one bank). 2-step shfl_xor combines partial dots.
__global__ __launch_bounds__(256) void k_bins(const u16* __restrict__ P,
        const float* __restrict__ R,
        int* __restrict__ binIdx, int* __restrict__ hist) {
    __shared__ float Rl[1280];
    const int tid = threadIdx.x;
    for (int idx = tid; idx < 1280; idx += 256) {
        int d = idx / 10, i = idx - d*10;
        int row = (d & 31)*4 + (d >> 5);
        Rl[row*10 + i] = R[d*100 + i];
    }
    __syncthreads();
    const int gp4 = blockIdx.x*256 + tid;    // grid sized exactly: TOTPTS*4
    const int point = gp4 >> 2, seg = gp4 & 3;
    float acc[10];
    #pragma unroll
    for (int i = 0; i < 10; ++i) acc[i] = 0.f;
    const uint4* hr = (const uint4*)(P + (size_t)point*256 + seg*32);
    const uint4* lr = (const uint4*)(P + (size_t)point*256 + 128 + seg*32);
    #pragma unroll
    for (int c = 0; c < 4; ++c) {
        uint4 hv = hr[c], lv = lr[c];
        float x[8];
        x[0] = f16bits((u16)(hv.x & 0xffff)) + f16bits((u16)(lv.x & 0xffff));
        x[1] = f16bits((u16)(hv.x >> 16))    + f16bits((u16)(lv.x >> 16));
        x[2] = f16bits((u16)(hv.y & 0xffff)) + f16bits((u16)(lv.y & 0xffff));
        x[3] = f16bits((u16)(hv.y >> 16))    + f16bits((u16)(lv.y >> 16));
        x[4] = f16bits((u16)(hv.z & 0xffff)) + f16bits((u16)(lv.z & 0xffff));
        x[5] = f16bits((u16)(hv.z >> 16))    + f16bits((u16)(lv.z >> 16));
        x[6] = f16bits((u16)(hv.w & 0xffff)) + f16bits((u16)(lv.w & 0xffff));
        x[7] = f16bits((u16)(hv.w >> 16))    + f16bits((u16)(lv.w >> 16));
        #pragma unroll
        for (int e = 0; e < 8; ++e) {
            const float* rr = &Rl[((c*8 + e)*4 + seg)*10];
            #pragma unroll
            for (int i = 0; i < 10; ++i) acc[i] += x[e]*rr[i];
        }
    }
    // combine the 4 seg-partials (lanes 4k..4k+3)
    #pragma unroll
    for (int i = 0; i < 10; ++i) {
        acc[i] += __shfl_xor(acc[i], 1, 64);
        acc[i] += __shfl_xor(acc[i], 2, 64);
    }
    if (seg != 0) return;
    float best = acc[0]; int bi = 0;
    #pragma unroll
    for (int i = 1; i < 10; ++i) if (acc[i] > best) { best = acc[i]; bi = i; }
    #pragma unroll
    for (int i = 0; i < 10; ++i) { float v = -acc[i]; if (v > best) { best = v; bi = 10+i; } }
    binIdx[point] = bi;
    atomicAdd(&hist[(point/NPTS)*NBINS + bi], 1);
}

// stable counting-sort scatter: one block per (batch,bin)
__global__ __launch_bounds__(256) void k_sort(const int* __restrict__ binIdx,
        const int* __restrict__ hist, int* __restrict__ sortedIdx) {
    const int b = blockIdx.x / NBINS;
    const int bin = blockIdx.x % NBINS;
    const int tid = threadIdx.x;
    __shared__ int wtot[4];
    int off = 0;
    for (int k = 0; k < bin; ++k) off += hist[b*NBINS + k];
    const int* bptr = binIdx + b*NPTS;
    int* sptr = sortedIdx + b*NPTS;
    const int lane = tid & 63, wid = tid >> 6;
    for (int c = 0; c < 40; ++c) {
        int i = c*256 + tid;
        bool pred = (i < NPTS) && (bptr[i] == bin);
        unsigned long long mask = __ballot(pred);
        int rank = __popcll(mask & ((1ULL << lane) - 1ULL));
        if (lane == 0) wtot[wid] = __popcll(mask);
        __syncthreads();
        int prefix = 0;
        #pragma unroll
        for (int w = 0; w < 4; ++w) prefix += (w < wid) ? wtot[w] : 0;
        int total = wtot[0]+wtot[1]+wtot[2]+wtot[3];
        if (pred) sptr[off + prefix + rank] = i;
        off += total;
        __syncthreads();
    }
}

// insert (v,p) into sorted-desc 5-list, strict > (candidates arrive ascending p)
#define INS_STRICT(VV,PP,v,p) do { \
  if ((v) > VV[4]) { \
    if ((v) > VV[3]) { VV[4]=VV[3]; PP[4]=PP[3]; \
      if ((v) > VV[2]) { VV[3]=VV[2]; PP[3]=PP[2]; \
        if ((v) > VV[1]) { VV[2]=VV[1]; PP[2]=PP[1]; \
          if ((v) > VV[0]) { VV[1]=VV[0]; PP[1]=PP[0]; VV[0]=(v); PP[0]=(p); } \
          else { VV[1]=(v); PP[1]=(p); } } \
        else { VV[2]=(v); PP[2]=(p); } } \
      else { VV[3]=(v); PP[3]=(p); } } \
    else { VV[4]=(v); PP[4]=(p); } } } while(0)

// tie-aware better-than: (v desc, p asc) — exact lax.top_k semantics
#define BT(va,pa,vb,pb) (((va) > (vb)) || (((va) == (vb)) && ((pa) < (pb))))
#define INS_TIE(VV,PP,v,p) do { \
  if (BT(v,p,VV[4],PP[4])) { \
    if (BT(v,p,VV[3],PP[3])) { VV[4]=VV[3]; PP[4]=PP[3]; \
      if (BT(v,p,VV[2],PP[2])) { VV[3]=VV[2]; PP[3]=PP[2]; \
        if (BT(v,p,VV[1],PP[1])) { VV[2]=VV[1]; PP[2]=PP[1]; \
          if (BT(v,p,VV[0],PP[0])) { VV[1]=VV[0]; PP[1]=PP[0]; VV[0]=(v); PP[0]=(p); } \
          else { VV[1]=(v); PP[1]=(p); } } \
        else { VV[2]=(v); PP[2]=(p); } } \
      else { VV[3]=(v); PP[3]=(p); } } \
    else { VV[4]=(v); PP[4]=(p); } } } while(0)

// Gram via f16 MFMA with pre-scaled split operands (zero runtime scaling):
//   acc = Hs_a·D_b + D_a·Hs_b + Hs_a·Hs_b ;  S = acc·2^-12
// (unchanged from round 4 — verified at ~90 µs; see prior round notes).
__global__ __launch_bounds__(256, 4) void k_gram(const u16* __restrict__ P,
        const int* __restrict__ sortedIdx, float* __restrict__ pV, int* __restrict__ pP) {
    __shared__ int gIdx[512];
    __shared__ __align__(16) union ShU {
        struct { u16 H[128][40]; u16 L[128][40]; } bs;   // 20480 B
        float T[64][132];                                // 33792 B
    } sh;
    const int tid = threadIdx.x;
    const int unit = blockIdx.x / 160;      // rowTile*4 + ch
    const int grp  = blockIdx.x - unit*160;
    const int rowTile = unit >> 2, ch = unit & 3;
    const int b = grp / NBINS, g = grp - b*NBINS;
    for (int i = tid; i < 512; i += 256) gIdx[i] = sortedIdx[b*NPTS + g*500 + min(i, 499)];
    __syncthreads();

    const int w    = tid >> 6;              // wave 0..3: rows w*32..w*32+31
    const int lane = tid & 63;
    const int l15  = lane & 15, l4 = lane >> 4;
    const int rowBase = rowTile * 128;

    const size_t ebase = (size_t)b * NPTS * 256;   // halfwords
    const u16* PB = P + ebase;
    const u16* pA0 = PB + (size_t)gIdx[rowBase + w*32 +      l15]*256 + l4*8;
    const u16* pA1 = PB + (size_t)gIdx[rowBase + w*32 + 16 + l15]*256 + l4*8;

    // stager role: thread t copies the 64B ks-chunk of col (t>>1), part (t&1)
    const int scol = tid >> 1, spart = tid & 1;
    const u16* pS = PB + (size_t)gIdx[ch*128 + scol]*256 + spart*128;
    u16* dS = spart ? &sh.bs.L[scol][0] : &sh.bs.H[scol][0];

    f32x4 acc[2][8];
    const f32x4 z4 = {0.f, 0.f, 0.f, 0.f};
    #pragma unroll
    for (int rf = 0; rf < 2; ++rf)
        #pragma unroll
        for (int cf = 0; cf < 8; ++cf) acc[rf][cf] = z4;

    // prologue: stage regs for ks=0
    uint4 s0, s1, s2, s3;
    { const uint4* s = (const uint4*)pS; s0 = s[0]; s1 = s[1]; s2 = s[2]; s3 = s[3]; }

    #pragma unroll
    for (int ks = 0; ks < 4; ++ks) {
        __syncthreads();                    // prior k-step's LDS reads done
        {   // write staged regs (data already in flight / in regs)
            uint4* d = (uint4*)dS;
            d[0] = s0; d[1] = s1; d[2] = s2; d[3] = s3;
        }
        if (ks < 3) {                       // prefetch next chunk: latency
            const uint4* s = (const uint4*)(pS + (ks+1)*32);   // hides under MFMA
            s0 = s[0]; s1 = s[1]; s2 = s[2]; s3 = s[3];
        }
        const int oH = ks*32, oD = 128 + ks*32;
        const f16x8 aH0 = *(const f16x8*)(pA0 + oH);
        const f16x8 aD0 = *(const f16x8*)(pA0 + oD);
        const f16x8 aH1 = *(const f16x8*)(pA1 + oH);
        const f16x8 aD1 = *(const f16x8*)(pA1 + oD);
        __syncthreads();                    // staged data visible
        #pragma unroll
        for (int cf = 0; cf < 8; ++cf) {
            const int col = cf*16 + l15;
            const f16x8 bH = *(const f16x8*)&sh.bs.H[col][l4*8];
            const f16x8 bD = *(const f16x8*)&sh.bs.L[col][l4*8];
            acc[0][cf] = __builtin_amdgcn_mfma_f32_16x16x32_f16(aH0, bD, acc[0][cf], 0, 0, 0);
            acc[1][cf] = __builtin_amdgcn_mfma_f32_16x16x32_f16(aH1, bD, acc[1][cf], 0, 0, 0);
            acc[0][cf] = __builtin_amdgcn_mfma_f32_16x16x32_f16(aD0, bH, acc[0][cf], 0, 0, 0);
            acc[1][cf] = __builtin_amdgcn_mfma_f32_16x16x32_f16(aD1, bH, acc[1][cf], 0, 0, 0);
            acc[0][cf] = __builtin_amdgcn_mfma_f32_16x16x32_f16(aH0, bH, acc[0][cf], 0, 0, 0);
            acc[1][cf] = __builtin_amdgcn_mfma_f32_16x16x32_f16(aH1, bH, acc[1][cf], 0, 0, 0);
        }
    }
    __syncthreads();                        // k-loop LDS reads done; reuse as T

    // ---- epilogue: per rf-half, LDS transpose then 4-thread/row top-5 ----
    const float sc = 2.44140625e-4f;        // 2^-12, applied to survivors only
    const int rT = tid >> 2;                // 0..63: T-row this thread reduces
    const int q  = tid & 3;                 // sub-chunks c4 = 4t+q (interleaved)
    const bool chk = (ch == 3);             // cols >= 116 invalid when ch==3
    #pragma unroll
    for (int rf = 0; rf < 2; ++rf) {
        #pragma unroll
        for (int cf = 0; cf < 8; ++cf) {
            const int col = cf*16 + l15;
            const int r0  = w*16 + l4*4;
            #pragma unroll
            for (int j = 0; j < 4; ++j) sh.T[r0+j][col] = acc[rf][cf][j];
        }
        __syncthreads();
        float lv[5]; int lp[5];
        #pragma unroll
        for (int p5 = 0; p5 < 5; ++p5) { lv[p5] = -3.4e38f; lp[p5] = 0x7fffffff; }
        const float* Tr = &sh.T[rT][0];
        #pragma unroll
        for (int t = 0; t < 8; ++t) {
            const int c4 = t*4 + q;         // ascending cpos; distinct bank-quads
            float4 v4 = *(const float4*)&Tr[c4*4];
            float vv4[4] = {v4.x, v4.y, v4.z, v4.w};
            #pragma unroll
            for (int e = 0; e < 4; ++e) {
                const int cloc = c4*4 + e;
                if (!chk || cloc < 116)     // 500-384: valid cols for ch==3
                    INS_STRICT(lv, lp, vv4[e], ch*128 + cloc);
            }
        }
        #pragma unroll
        for (int m = 1; m < 4; m <<= 1) {
            float qv[5]; int qp[5];
            #pragma unroll
            for (int p5 = 0; p5 < 5; ++p5) {
                qv[p5] = __shfl_xor(lv[p5], m, 64);
                qp[p5] = __shfl_xor(lp[p5], m, 64);
            }
            #pragma unroll
            for (int p5 = 0; p5 < 5; ++p5) INS_TIE(lv, lp, qv[p5], qp[p5]);
        }
        if (q == 0) {
            const int rpos = rowBase + (rT>>4)*32 + rf*16 + (rT&15);
            if (rpos < 500) {
                const int pbase = ((grp*4 + ch)*PROWS + rpos)*5;
                #pragma unroll
                for (int p5 = 0; p5 < 5; ++p5) { pV[pbase+p5] = lv[p5]*sc; pP[pbase+p5] = lp[p5]; }
            }
        }
        __syncthreads();
    }
}

// fused merge + edge MLP, 4 threads per src point.
// v5: w1t rows interleaved r=(j&31)*4+(j>>5) — the 4 quarters of a wave now
// read adjacent rows (bank starts offset by 4) instead of rows 32 apart
// (all on one bank, 4-way conflict on every float4 -> 25.4M conflict cycles).
// b1/W2 folded into row slots 33/34 (same fix). Values/order bit-identical.
__global__ __launch_bounds__(256) void k_edge(const float* __restrict__ X,
        const float* __restrict__ W1, const float* __restrict__ b1,
        const float* __restrict__ W2, const float* __restrict__ b2,
        const float* __restrict__ pV, const int* __restrict__ pP,
        const int* __restrict__ sortedIdx, float* __restrict__ out) {
    __shared__ float w1t[128*36];
    const int tid = threadIdx.x;
    for (int idx = tid; idx < 33*128; idx += 256) {
        int f = idx >> 7, j = idx & 127;
        w1t[((j & 31)*4 + (j >> 5))*36 + f] = W1[idx];
    }
    if (tid < 128) {
        int r = ((tid & 31)*4 + (tid >> 5))*36;
        w1t[r + 33] = b1[tid];
        w1t[r + 34] = W2[tid];
    }
    __syncthreads();
    int rid4 = blockIdx.x*256 + tid;
    if (rid4 >= NGRP*BINSZ*4) return;
    const int rid = rid4 >> 2, quarter = rid4 & 3;
    const int grp = rid / BINSZ;
    const int rowLocal = rid - grp*BINSZ;
    const int b = grp / NBINS, g = grp - b*NBINS;
    // ---- merge 4 ch-partials (duplicated across the 4 quarters; deterministic) ----
    float lv[5]; int lp[5];
    {
        int pbase = (grp*4*PROWS + rowLocal)*5;
        #pragma unroll
        for (int j = 0; j < 5; ++j) { lv[j] = pV[pbase+j]; lp[j] = pP[pbase+j]; }
    }
    #pragma unroll
    for (int chh = 1; chh < 4; ++chh) {
        int pbase = ((grp*4 + chh)*PROWS + rowLocal)*5;
        #pragma unroll
        for (int j = 0; j < 5; ++j) {
            float v = pV[pbase+j]; int p = pP[pbase+j];
            INS_TIE(lv, lp, v, p);
        }
    }
    const int* sIdx = sortedIdx + b*NPTS + g*BINSZ;
    const int src = sIdx[rowLocal];
    int dd[5]; float vv[5];
    #pragma unroll
    for (int j = 0; j < 5; ++j) {
        dd[j] = sIdx[lp[j]];
        vv[j] = 1.f/(1.f + expf(-lv[j]));
    }
    #define CSWAP(i,j) { if (dd[i] > dd[j]) { int td=dd[i];dd[i]=dd[j];dd[j]=td; \
                         float tf=vv[i];vv[i]=vv[j];vv[j]=tf; } }
    CSWAP(0,1) CSWAP(3,4) CSWAP(2,4) CSWAP(2,3) CSWAP(1,4)
    CSWAP(0,3) CSWAP(0,2) CSWAP(1,3) CSWAP(1,2)
    #undef CSWAP
    const int base = b*EDGES_PER_BATCH + src*5;
    if (quarter == 0) {
        #pragma unroll
        for (int e = 0; e < 5; ++e) {
            out[EDGE_TOT   + base + e] = (float)src;
            out[2*EDGE_TOT + base + e] = (float)dd[e];
        }
    }
    // ---- edge MLP over j-range [quarter*32, quarter*32+32) ----
    float4 xs[4];
    {
        const float4* xp = (const float4*)(X + ((size_t)b*NPTS + src)*NFEAT);
        #pragma unroll
        for (int q = 0; q < 4; ++q) xs[q] = xp[q];
    }
    float4 xd[5][4];
    #pragma unroll
    for (int e = 0; e < 5; ++e) {
        const float4* xp = (const float4*)(X + ((size_t)b*NPTS + dd[e])*NFEAT);
        #pragma unroll
        for (int q = 0; q < 4; ++q) xd[e][q] = xp[q];
    }
    float acc[5] = {0.f,0.f,0.f,0.f,0.f};
    for (int jj = 0; jj < 32; ++jj) {       // j = quarter*32 + jj (same order)
        const float* wr = &w1t[(jj*4 + quarter)*36];
        float4 ws0 = ((const float4*)wr)[0];
        float4 ws1 = ((const float4*)wr)[1];
        float4 ws2 = ((const float4*)wr)[2];
        float4 ws3 = ((const float4*)wr)[3];
        float4 u0  = ((const float4*)(wr+16))[0];
        float4 u1  = ((const float4*)(wr+16))[1];
        float4 u2  = ((const float4*)(wr+16))[2];
        float4 u3  = ((const float4*)(wr+16))[3];
        float w32 = wr[32];
        float b1j = wr[33];
        float w2j = wr[34];
        float sh = b1j
            + xs[0].x*ws0.x + xs[0].y*ws0.y + xs[0].z*ws0.z + xs[0].w*ws0.w
            + xs[1].x*ws1.x + xs[1].y*ws1.y + xs[1].z*ws1.z + xs[1].w*ws1.w
            + xs[2].x*ws2.x + xs[2].y*ws2.y + xs[2].z*ws2.z + xs[2].w*ws2.w
            + xs[3].x*ws3.x + xs[3].y*ws3.y + xs[3].z*ws3.z + xs[3].w*ws3.w;
        #pragma unroll
        for (int e = 0; e < 5; ++e) {
            float h = sh
                + xd[e][0].x*u0.x + xd[e][0].y*u0.y + xd[e][0].z*u0.z + xd[e][0].w*u0.w
                + xd[e][1].x*u1.x + xd[e][1].y*u1.y + xd[e][1].z*u1.z + xd[e][1].w*u1.w
                + xd[e][2].x*u2.x + xd[e][2].y*u2.y + xd[e][2].z*u2.z + xd[e][2].w*u2.w
                + xd[e][3].x*u3.x + xd[e][3].y*u3.y + xd[e][3].z*u3.z + xd[e][3].w*u3.w;
            h += vv[e]*w32;
            h = (h > 0.f) ? h : expm1f(h);
            acc[e] += h * w2j;
        }
    }
    // pairwise reduce across the 4 quarters: ((q0+q1)+(q2+q3))
    #pragma unroll
    for (int e = 0; e < 5; ++e) {
        acc[e] += __shfl_xor(acc[e], 1, 64);
        acc[e] += __shfl_xor(acc[e], 2, 64);
    }
    if (quarter != 0) return;
    float b2v = b2[0];
    #pragma unroll
    for (int e = 0; e < 5; ++e) {
        out[base + e] = 1.f/(1.f + expf(-(acc[e] + b2v)));
    }
}

extern "C" void kernel_launch(void* const* d_in, const int* in_sizes, int n_in,
                              void* d_out, int out_size, void* d_ws, size_t ws_size,
                              hipStream_t stream) {
    const float* X   = (const float*)d_in[0];
    const float* We1 = (const float*)d_in[1];
    const float* be1 = (const float*)d_in[2];
    const float* We2 = (const float*)d_in[3];
    const float* be2 = (const float*)d_in[4];
    const float* Wd1 = (const float*)d_in[5];
    const float* bd1 = (const float*)d_in[6];
    const float* Wd2 = (const float*)d_in[7];
    const float* bd2 = (const float*)d_in[8];
    const float* R   = (const float*)d_in[9];
    float* out = (float*)d_out;

    // workspace layout (~54 MB, unchanged footprint):
    // P[row][256] = [Hs|D] occupies exactly the old slab.
    u16* Pw         = (u16*)d_ws;                          // 80000*256 u16
    int*   binIdx   = (int*)(Pw + (size_t)TOTPTS*256);     // 80000
    int*   sortedIdx= binIdx + TOTPTS;                     // 80000
    int*   hist     = sortedIdx + TOTPTS;                  // 160
    float* pV       = (float*)(hist + NBATCH*NBINS);       // 160*4*512*5
    int*   pP       = (int*)(pV + (size_t)NGRP*4*PROWS*5); // 160*4*512*5

    k_enc  <<<TOTPTS/32, 256, 0, stream>>>(X, We1, be1, We2, be2, Pw, hist);
    k_bins <<<TOTPTS*4/256, 256, 0, stream>>>(Pw, R, binIdx, hist);
    k_sort <<<NBATCH*NBINS, 256, 0, stream>>>(binIdx, hist, sortedIdx);
    k_gram <<<NGRP*16, 256, 0, stream>>>(Pw, sortedIdx, pV, pP);
    k_edge <<<(NGRP*BINSZ*4+255)/256, 256, 0, stream>>>(X, Wd1, bd1, Wd2, bd2,
                                                        pV, pP, sortedIdx, out);
}